// Round 5
// baseline (122.714 us; speedup 1.0000x reference)
//
#include <hip/hip_runtime.h>
#include <hip/hip_bf16.h>
#include <cstdint>

#define B_ 4
#define T_ 2048
#define D_ 512
#define H_ 8

typedef __bf16 bf16x8 __attribute__((ext_vector_type(8)));
typedef __bf16 bf16x4 __attribute__((ext_vector_type(4)));
typedef float f32x4 __attribute__((ext_vector_type(4)));

// 0.125 (1/sqrt(Dh)) * log2(e), folded into Q so softmax uses exp2 directly
#define QSCALE 0.18033688011112042f
#define DEFER_THR 11.5415603f   // 8 * log2(e)

__device__ inline void gload_lds16(const void* g, void* l) {
    __builtin_amdgcn_global_load_lds(
        (const __attribute__((address_space(1))) void*)g,
        (__attribute__((address_space(3))) void*)l, 16, 0, 0);
}

// ---------------- cast fp32 -> bf16 for q and kv in one launch ----------------
__global__ void cast2_kernel(const float* __restrict__ qf, const float* __restrict__ kvf,
                             __bf16* __restrict__ qb, __bf16* __restrict__ kvb, int n4) {
    int stride = gridDim.x * blockDim.x;
    for (int i = blockIdx.x * blockDim.x + threadIdx.x; i < 2 * n4; i += stride) {
        const float* src = (i < n4) ? qf : kvf;
        __bf16* dst = (i < n4) ? qb : kvb;
        int j = (i < n4) ? i : i - n4;
        float4 v = reinterpret_cast<const float4*>(src)[j];
        bf16x4 o = { (__bf16)v.x, (__bf16)v.y, (__bf16)v.z, (__bf16)v.w };
        reinterpret_cast<bf16x4*>(dst)[j] = o;
    }
}

// ---------------- transpose all 4 weights (z selects) ----------------
__global__ void transpose_w4_kernel(const float* __restrict__ wq, const float* __restrict__ wk,
                                    const float* __restrict__ wv, const float* __restrict__ wo,
                                    __bf16* __restrict__ wqkvT, __bf16* __restrict__ woT) {
    __shared__ float tile[32][33];
    int z = blockIdx.z;
    const float* in = (z == 0) ? wq : (z == 1) ? wk : (z == 2) ? wv : wo;
    __bf16* out = (z < 3) ? wqkvT + (size_t)z * D_ * D_ : woT;
    int tx = threadIdx.x & 31, ty = threadIdx.x >> 5;
    int r0 = blockIdx.y * 32, c0 = blockIdx.x * 32;
#pragma unroll
    for (int i = 0; i < 4; i++)
        tile[ty + i * 8][tx] = in[(size_t)(r0 + ty + i * 8) * D_ + c0 + tx];
    __syncthreads();
#pragma unroll
    for (int i = 0; i < 4; i++)
        out[(size_t)(c0 + ty + i * 8) * D_ + r0 + tx] = (__bf16)tile[tx][ty + i * 8];
}

// ---------------- RoPE cos/sin table ----------------
__global__ void rope_table_kernel(float2* __restrict__ tab) {
    int i = blockIdx.x * 256 + threadIdx.x;     // T*32 entries
    int p = i >> 5, d2 = i & 31;
    float inv_ts = exp2f((float)d2 * (-13.28771237954945f / 32.0f));
    float ang = (float)p * inv_ts;
    float sv, cv;
    __sincosf(ang, &sv, &cv);
    tab[i] = make_float2(cv, sv);
}

// ---------------- tiled GEMM: 128x128 tile, BK=32, double-buffered LDS ----------------
// MODE 0: out = X @ woT^T + bo -> fp32 [M][512]
// MODE 3: fused QKV: WT is [1536][512]; segment 0/1 -> RMSNorm+RoPE bf16 heads
//         (segment 0 additionally folds QSCALE), segment 2 -> V^T bf16 [B*H][64][T]
template<int MODE>
__global__ __launch_bounds__(256, 2) void gemm_tile_kernel(
    const __bf16* __restrict__ Xq, const __bf16* __restrict__ Xkv,
    const __bf16* __restrict__ WT,
    const float* __restrict__ biasQ, const float* __restrict__ biasK,
    const float* __restrict__ biasV,
    float* __restrict__ outf, __bf16* __restrict__ qh, __bf16* __restrict__ kh,
    __bf16* __restrict__ vt,
    const float* __restrict__ scale_q, const float* __restrict__ scale_k,
    const int* __restrict__ qpos, const int* __restrict__ kpos,
    const float2* __restrict__ rtab, int M, int Ntot, int K) {
    __shared__ __bf16 Ab[2][128 * 32];
    __shared__ __bf16 Bb[2][128 * 32];

    const int tid = threadIdx.x;
    const int lane = tid & 63, widx = tid >> 6;
    const int lo = lane & 15, hi = lane >> 4;
    const int wm = widx >> 1, wn = widx & 1;

    // bijective XCD swizzle (gridDim.x % 8 == 0)
    const int nwg = gridDim.x;
    const int q8 = nwg >> 3;
    int bid = blockIdx.x;
    int swz = (bid & 7) * q8 + (bid >> 3);
    const int ntn = Ntot >> 7;
    const int m0 = (swz / ntn) << 7;
    const int nt = swz % ntn;
    const int n0g = nt << 7;                       // row base in WT
    const int seg = (MODE == 3) ? (nt >> 2) : 0;   // 0:Q 1:K 2:V
    const __bf16* X = (MODE == 3 && seg > 0) ? Xkv : Xq;

    const int srow = tid >> 2;
    const int sslot = tid & 3;

    f32x4 acc[4][4] = {};

    auto stage = [&](int kc, int bufi) {
#pragma unroll
        for (int i = 0; i < 2; i++) {
            int row = i * 64 + srow;
            int cs = sslot ^ ((row >> 1) & 3);
            gload_lds16(X + (size_t)(m0 + row) * K + kc + cs * 8,
                        &Ab[bufi][(i * 64 + widx * 16) * 32]);
        }
#pragma unroll
        for (int i = 0; i < 2; i++) {
            int row = i * 64 + srow;
            int cs = sslot ^ ((row >> 1) & 3);
            gload_lds16(WT + (size_t)(n0g + row) * K + kc + cs * 8,
                        &Bb[bufi][(i * 64 + widx * 16) * 32]);
        }
    };

    const int nks = K >> 5;
    stage(0, 0);
    __syncthreads();
    int cur = 0;

    for (int ks = 0; ks < nks; ks++) {
        if (ks + 1 < nks) stage((ks + 1) << 5, cur ^ 1);

        bf16x8 a[4], bvec[4];
#pragma unroll
        for (int mf = 0; mf < 4; mf++) {
            int R = wm * 64 + mf * 16 + lo;
            a[mf] = *reinterpret_cast<const bf16x8*>(&Ab[cur][R * 32 + ((hi ^ ((R >> 1) & 3)) << 3)]);
        }
#pragma unroll
        for (int nf = 0; nf < 4; nf++) {
            int R = wn * 64 + nf * 16 + lo;
            bvec[nf] = *reinterpret_cast<const bf16x8*>(&Bb[cur][R * 32 + ((hi ^ ((R >> 1) & 3)) << 3)]);
        }
#pragma unroll
        for (int mf = 0; mf < 4; mf++)
#pragma unroll
            for (int nf = 0; nf < 4; nf++)
                acc[mf][nf] = __builtin_amdgcn_mfma_f32_16x16x32_bf16(a[mf], bvec[nf], acc[mf][nf], 0, 0, 0);

        __syncthreads();
        cur ^= 1;
    }

    const int mrow0 = m0 + wm * 64;

    if (MODE == 0) {
        const int ncol0 = n0g + wn * 64;
        float bs[4];
#pragma unroll
        for (int nf = 0; nf < 4; nf++) bs[nf] = biasQ[ncol0 + nf * 16 + lo];
#pragma unroll
        for (int mf = 0; mf < 4; mf++)
#pragma unroll
            for (int nf = 0; nf < 4; nf++)
#pragma unroll
                for (int r = 0; r < 4; r++) {
                    int row = mrow0 + mf * 16 + hi * 4 + r;
                    outf[(size_t)row * Ntot + ncol0 + nf * 16 + lo] = acc[mf][nf][r] + bs[nf];
                }
    } else {
        const int ncol0 = ((nt & 3) << 7) + wn * 64;   // within 512-wide segment
        const int h = ncol0 >> 6;
        const float* bias = (seg == 0) ? biasQ : (seg == 1) ? biasK : biasV;
        float bs[4];
#pragma unroll
        for (int nf = 0; nf < 4; nf++) bs[nf] = bias[ncol0 + nf * 16 + lo];

        if (seg < 2) {
            const float* scale = seg ? scale_k : scale_q;
            const int* pos = seg ? kpos : qpos;
            __bf16* dst0 = seg ? kh : qh;
            const float qmul = seg ? 1.0f : QSCALE;
            float sc4[4];
#pragma unroll
            for (int nf = 0; nf < 4; nf++) sc4[nf] = (1.0f + scale[nf * 16 + lo]) * qmul;
#pragma unroll
            for (int mf = 0; mf < 4; mf++) {
#pragma unroll
                for (int r = 0; r < 4; r++) {
                    int row = mrow0 + mf * 16 + hi * 4 + r;
                    float y0 = acc[mf][0][r] + bs[0];
                    float y1 = acc[mf][1][r] + bs[1];
                    float y2 = acc[mf][2][r] + bs[2];
                    float y3 = acc[mf][3][r] + bs[3];
                    float ps = y0 * y0 + y1 * y1 + y2 * y2 + y3 * y3;
#pragma unroll
                    for (int off = 1; off < 16; off <<= 1) ps += __shfl_xor(ps, off);
                    float rmsf = rsqrtf(ps * (1.0f / 64.0f) + 1e-6f);
                    int p = pos[row];
                    float2 c0 = rtab[p * 32 + lo];
                    float2 c1 = rtab[p * 32 + 16 + lo];
                    float z0 = y0 * rmsf * sc4[0];
                    float z1 = y1 * rmsf * sc4[1];
                    float z2 = y2 * rmsf * sc4[2];
                    float z3 = y3 * rmsf * sc4[3];
                    int b = row >> 11, t = row & (T_ - 1);
                    __bf16* dst = dst0 + ((size_t)(b * H_ + h) * T_ + t) * 64;
                    dst[lo]      = (__bf16)(z0 * c0.x - z2 * c0.y);
                    dst[16 + lo] = (__bf16)(z1 * c1.x - z3 * c1.y);
                    dst[32 + lo] = (__bf16)(z2 * c0.x + z0 * c0.y);
                    dst[48 + lo] = (__bf16)(z3 * c1.x + z1 * c1.y);
                }
            }
        } else {
#pragma unroll
            for (int mf = 0; mf < 4; mf++) {
                int row0 = mrow0 + mf * 16 + hi * 4;
                int b = row0 >> 11, t0 = row0 & (T_ - 1);
#pragma unroll
                for (int nf = 0; nf < 4; nf++) {
                    int d = nf * 16 + lo;
                    bf16x4 pk = { (__bf16)(acc[mf][nf][0] + bs[nf]), (__bf16)(acc[mf][nf][1] + bs[nf]),
                                  (__bf16)(acc[mf][nf][2] + bs[nf]), (__bf16)(acc[mf][nf][3] + bs[nf]) };
                    *reinterpret_cast<bf16x4*>(vt + ((size_t)(b * H_ + h) * 64 + d) * T_ + t0) = pk;
                }
            }
        }
    }
}

// ---------------- causal flash attention: 128-row strips, 32 q-rows/wave ----------------
// qh (pre-scaled by QSCALE), kh: bf16 [B*H][T][64]; vt: bf16 [B*H][64][T].
// Grid (bh=32, 16 strips), strip sid = 15-blockIdx.y (longest first), ntiles = 2*sid+2.
// Wave owns 32 q rows (2 16-row frags). Swapped QK^T: lane holds S[q=lo][kv=16f+4hi+r].
// Softmax in exp2 units (scale folded into Q). Defer-max (T13).
__global__ __launch_bounds__(256, 3) void attn_kernel(const __bf16* __restrict__ qh,
                                                      const __bf16* __restrict__ kh,
                                                      const __bf16* __restrict__ vt,
                                                      __bf16* __restrict__ attn) {
    __shared__ __bf16 kbuf[2][64 * 64];
    __shared__ __bf16 vbuf[2][64 * 64];
    __shared__ __bf16 plds[4][32][72];

    const int lane = threadIdx.x & 63, widx = threadIdx.x >> 6;
    const int lo = lane & 15, hi = lane >> 4;
    const int bh = blockIdx.x;
    const int sid = 15 - blockIdx.y;          // longest strips dispatched first
    const int ntiles = 2 * sid + 2;
    const int qb = sid * 128 + widx * 32;
    const __bf16* Qg = qh + (size_t)bh * T_ * 64;
    const __bf16* Kg = kh + (size_t)bh * T_ * 64;
    const __bf16* Vg = vt + (size_t)bh * 64 * T_;
    const int b = bh >> 3, h = bh & 7;

    const int srow = lane >> 3;
    const int sslot = lane & 7;
    const int schunk = sslot ^ srow;

    bf16x8 qa[2][2];
#pragma unroll
    for (int g = 0; g < 2; g++)
#pragma unroll
        for (int c = 0; c < 2; c++)
            qa[g][c] = *reinterpret_cast<const bf16x8*>(
                Qg + (size_t)(qb + g * 16 + lo) * 64 + c * 32 + hi * 8);

    f32x4 o[2][4] = {};
    float m[2] = { -1e30f, -1e30f }, l[2] = { 0.0f, 0.0f };

    auto stage = [&](int tile, int bufi) {
        const int kvb0 = tile * 64;
#pragma unroll
        for (int i = 0; i < 2; i++) {
            int r = widx * 16 + i * 8 + srow;
            gload_lds16(Kg + (size_t)(kvb0 + r) * 64 + schunk * 8,
                        &kbuf[bufi][(widx * 16 + i * 8) * 64]);
        }
#pragma unroll
        for (int i = 0; i < 2; i++) {
            int r = widx * 16 + i * 8 + srow;
            gload_lds16(Vg + (size_t)r * T_ + kvb0 + schunk * 8,
                        &vbuf[bufi][(widx * 16 + i * 8) * 64]);
        }
    };

    stage(0, 0);
    __syncthreads();
    int cur = 0;

    for (int j = 0; j < ntiles; ++j) {
        if (j + 1 < ntiles) stage(j + 1, cur ^ 1);

        const int dj = j - 2 * sid;                 // >=0 only for the last two tiles
        const bool active = !(dj == 1 && widx < 2); // fully-masked wave: skip compute
        if (active) {
            // ---- S^T = K x Q^T : s[g][f][r] = S[q=qb+g*16+lo][kv=j*64+16f+4hi+r] ----
            f32x4 s[2][4] = {};
            __builtin_amdgcn_s_setprio(1);
#pragma unroll
            for (int c = 0; c < 2; c++) {
#pragma unroll
                for (int f = 0; f < 4; f++) {
                    int R = f * 16 + lo;
                    int C = c * 4 + hi;
                    bf16x8 kb = *reinterpret_cast<const bf16x8*>(
                        &kbuf[cur][R * 64 + ((C ^ (lo & 7)) << 3)]);
                    s[0][f] = __builtin_amdgcn_mfma_f32_16x16x32_bf16(kb, qa[0][c], s[0][f], 0, 0, 0);
                    s[1][f] = __builtin_amdgcn_mfma_f32_16x16x32_bf16(kb, qa[1][c], s[1][f], 0, 0, 0);
                }
            }
            __builtin_amdgcn_s_setprio(0);

            // ---- mask + in-lane max ----
            const bool diag = (dj == 0 && widx < 2) || (dj == 1 && widx >= 2);
            float pm[2] = { -1e30f, -1e30f };
#pragma unroll
            for (int g = 0; g < 2; g++)
#pragma unroll
                for (int f = 0; f < 4; f++)
#pragma unroll
                    for (int r = 0; r < 4; r++) {
                        float v = s[g][f][r];
                        if (diag && (j * 64 + f * 16 + hi * 4 + r > qb + g * 16 + lo)) v = -1e30f;
                        s[g][f][r] = v;
                        pm[g] = fmaxf(pm[g], v);
                    }
#pragma unroll
            for (int g = 0; g < 2; g++) {
                pm[g] = fmaxf(pm[g], __shfl_xor(pm[g], 16));
                pm[g] = fmaxf(pm[g], __shfl_xor(pm[g], 32));
            }

            // ---- defer-max (T13) ----
            if (!__all(fmaxf(pm[0] - m[0], pm[1] - m[1]) <= DEFER_THR)) {
#pragma unroll
                for (int g = 0; g < 2; g++) {
                    float mn = fmaxf(m[g], pm[g]);
                    float alpha = exp2f(m[g] - mn);
                    l[g] *= alpha;
#pragma unroll
                    for (int n = 0; n < 4; n++)
#pragma unroll
                        for (int r = 0; r < 4; r++) o[g][n][r] *= alpha;
                    m[g] = mn;
                }
            }

            // ---- exp2 + in-lane sum + P pack ----
            bf16x4 pk[2][4];
#pragma unroll
            for (int g = 0; g < 2; g++) {
                float ps = 0.0f;
#pragma unroll
                for (int f = 0; f < 4; f++)
#pragma unroll
                    for (int r = 0; r < 4; r++) {
                        float e = exp2f(s[g][f][r] - m[g]);
                        ps += e;
                        pk[g][f][r] = (__bf16)e;
                    }
                ps += __shfl_xor(ps, 16);
                ps += __shfl_xor(ps, 32);
                l[g] += ps;
            }

            // ---- P -> LDS -> B-fragments ----
#pragma unroll
            for (int g = 0; g < 2; g++)
#pragma unroll
                for (int f = 0; f < 4; f++)
                    *reinterpret_cast<bf16x4*>(&plds[widx][g * 16 + lo][f * 16 + hi * 4]) = pk[g][f];
            bf16x8 pa[2][2];
#pragma unroll
            for (int g = 0; g < 2; g++)
#pragma unroll
                for (int c = 0; c < 2; c++)
                    pa[g][c] = *reinterpret_cast<const bf16x8*>(
                        &plds[widx][g * 16 + lo][c * 32 + hi * 8]);

            // ---- O^T += V^T x P^T ----
            __builtin_amdgcn_s_setprio(1);
#pragma unroll
            for (int n = 0; n < 4; n++) {
#pragma unroll
                for (int c = 0; c < 2; c++) {
                    int R = n * 16 + lo;
                    int C = c * 4 + hi;
                    bf16x8 vb = *reinterpret_cast<const bf16x8*>(
                        &vbuf[cur][R * 64 + ((C ^ (lo & 7)) << 3)]);
                    o[0][n] = __builtin_amdgcn_mfma_f32_16x16x32_bf16(vb, pa[0][c], o[0][n], 0, 0, 0);
                    o[1][n] = __builtin_amdgcn_mfma_f32_16x16x32_bf16(vb, pa[1][c], o[1][n], 0, 0, 0);
                }
            }
            __builtin_amdgcn_s_setprio(0);
        }

        __syncthreads();
        cur ^= 1;
    }

#pragma unroll
    for (int g = 0; g < 2; g++) {
        const float inv = 1.0f / l[g];
        const int qrow = qb + g * 16 + lo;
#pragma unroll
        for (int n = 0; n < 4; n++) {
            bf16x4 pk = { (__bf16)(o[g][n][0] * inv), (__bf16)(o[g][n][1] * inv),
                          (__bf16)(o[g][n][2] * inv), (__bf16)(o[g][n][3] * inv) };
            *reinterpret_cast<bf16x4*>(attn + ((size_t)b * T_ + qrow) * D_ + h * 64 + n * 16 + hi * 4) = pk;
        }
    }
}

extern "C" void kernel_launch(void* const* d_in, const int* in_sizes, int n_in,
                              void* d_out, int out_size, void* d_ws, size_t ws_size,
                              hipStream_t stream) {
    const float* q  = (const float*)d_in[0];
    const float* kv = (const float*)d_in[1];
    const int* qpos = (const int*)d_in[3];
    const int* kpos = (const int*)d_in[4];
    const float* wq = (const float*)d_in[5];
    const float* bq = (const float*)d_in[6];
    const float* wk = (const float*)d_in[7];
    const float* bk = (const float*)d_in[8];
    const float* wv = (const float*)d_in[9];
    const float* bv = (const float*)d_in[10];
    const float* scale_q = (const float*)d_in[11];
    const float* scale_k = (const float*)d_in[12];
    const float* wo = (const float*)d_in[13];
    const float* bo = (const float*)d_in[14];
    float* out = (float*)d_out;

    char* ws = (char*)d_ws;
    size_t off = 0;
    auto alloc = [&](size_t bytes) {
        void* p = ws + off;
        off += (bytes + 255) & ~(size_t)255;
        return p;
    };
    const size_t MD = (size_t)B_ * T_ * D_;
    __bf16* qb16   = (__bf16*)alloc(MD * 2);
    __bf16* kvb16  = (__bf16*)alloc(MD * 2);
    __bf16* wqkvT  = (__bf16*)alloc((size_t)3 * D_ * D_ * 2);
    __bf16* woT    = (__bf16*)alloc((size_t)D_ * D_ * 2);
    __bf16* qh  = (__bf16*)alloc(MD * 2);
    __bf16* kh  = (__bf16*)alloc(MD * 2);
    __bf16* vt  = (__bf16*)alloc(MD * 2);
    float2* rtab = (float2*)alloc((size_t)T_ * 32 * sizeof(float2));
    __bf16* attn = qb16;  // reuse: qb16 dead after QKV GEMM

    cast2_kernel<<<2048, 256, 0, stream>>>(q, kv, qb16, kvb16, (int)(MD / 4));
    transpose_w4_kernel<<<dim3(16, 16, 4), 256, 0, stream>>>(wq, wk, wv, wo, wqkvT, woT);
    rope_table_kernel<<<(T_ * 32) / 256, 256, 0, stream>>>(rtab);

    const int M = B_ * T_;
    // fused QKV projection + RMSNorm/RoPE/V-transpose epilogues: N=1536 -> 768 blocks
    gemm_tile_kernel<3><<<(M / 128) * (3 * D_ / 128), 256, 0, stream>>>(
        qb16, kvb16, wqkvT, bq, bk, bv, nullptr, qh, kh, vt,
        scale_q, scale_k, qpos, kpos, rtab, M, 3 * D_, D_);
    // attention: grid (bh, strip), longest strips first; 128-row strips
    attn_kernel<<<dim3(B_ * H_, 16), 256, 0, stream>>>(qh, kh, vt, attn);
    // output projection
    gemm_tile_kernel<0><<<(M / 128) * (D_ / 128), 256, 0, stream>>>(
        attn, nullptr, woT, bo, nullptr, nullptr, out, nullptr, nullptr, nullptr,
        nullptr, nullptr, nullptr, nullptr, nullptr, M, D_, D_);
}

// Round 6
// 110.442 us; speedup vs baseline: 1.1111x; 1.1111x over previous
//
#include <hip/hip_runtime.h>
#include <hip/hip_bf16.h>
#include <cstdint>

#define B_ 4
#define T_ 2048
#define D_ 512
#define H_ 8

typedef __bf16 bf16x8 __attribute__((ext_vector_type(8)));
typedef __bf16 bf16x4 __attribute__((ext_vector_type(4)));
typedef float f32x4 __attribute__((ext_vector_type(4)));

// 0.125 (1/sqrt(Dh)) * log2(e), folded into Q so softmax uses exp2 directly
#define QSCALE 0.18033688011112042f
#define DEFER_THR 11.5415603f   // 8 * log2(e)

__device__ inline void gload_lds16(const void* g, void* l) {
    __builtin_amdgcn_global_load_lds(
        (const __attribute__((address_space(1))) void*)g,
        (__attribute__((address_space(3))) void*)l, 16, 0, 0);
}

// ---------------- cast fp32 -> bf16 for q and kv in one launch ----------------
__global__ void cast2_kernel(const float* __restrict__ qf, const float* __restrict__ kvf,
                             __bf16* __restrict__ qb, __bf16* __restrict__ kvb, int n4) {
    int stride = gridDim.x * blockDim.x;
    for (int i = blockIdx.x * blockDim.x + threadIdx.x; i < 2 * n4; i += stride) {
        const float* src = (i < n4) ? qf : kvf;
        __bf16* dst = (i < n4) ? qb : kvb;
        int j = (i < n4) ? i : i - n4;
        float4 v = reinterpret_cast<const float4*>(src)[j];
        bf16x4 o = { (__bf16)v.x, (__bf16)v.y, (__bf16)v.z, (__bf16)v.w };
        reinterpret_cast<bf16x4*>(dst)[j] = o;
    }
}

// ---------------- transpose all 4 weights (z selects) ----------------
__global__ void transpose_w4_kernel(const float* __restrict__ wq, const float* __restrict__ wk,
                                    const float* __restrict__ wv, const float* __restrict__ wo,
                                    __bf16* __restrict__ wqkvT, __bf16* __restrict__ woT) {
    __shared__ float tile[32][33];
    int z = blockIdx.z;
    const float* in = (z == 0) ? wq : (z == 1) ? wk : (z == 2) ? wv : wo;
    __bf16* out = (z < 3) ? wqkvT + (size_t)z * D_ * D_ : woT;
    int tx = threadIdx.x & 31, ty = threadIdx.x >> 5;
    int r0 = blockIdx.y * 32, c0 = blockIdx.x * 32;
#pragma unroll
    for (int i = 0; i < 4; i++)
        tile[ty + i * 8][tx] = in[(size_t)(r0 + ty + i * 8) * D_ + c0 + tx];
    __syncthreads();
#pragma unroll
    for (int i = 0; i < 4; i++)
        out[(size_t)(c0 + ty + i * 8) * D_ + r0 + tx] = (__bf16)tile[tx][ty + i * 8];
}

// ---------------- RoPE cos/sin table ----------------
__global__ void rope_table_kernel(float2* __restrict__ tab) {
    int i = blockIdx.x * 256 + threadIdx.x;     // T*32 entries
    int p = i >> 5, d2 = i & 31;
    float inv_ts = exp2f((float)d2 * (-13.28771237954945f / 32.0f));
    float ang = (float)p * inv_ts;
    float sv, cv;
    __sincosf(ang, &sv, &cv);
    tab[i] = make_float2(cv, sv);
}

// ---------------- tiled GEMM: 128x128 tile, BK=32, double-buffered LDS ----------------
// MODE 0: out = X @ woT^T + bo -> fp32 [M][512]
// MODE 3: fused QKV: WT is [1536][512]; segment 0/1 -> RMSNorm+RoPE bf16 heads
//         (segment 0 additionally folds QSCALE), segment 2 -> V^T bf16 [B*H][64][T]
template<int MODE>
__global__ __launch_bounds__(256, 2) void gemm_tile_kernel(
    const __bf16* __restrict__ Xq, const __bf16* __restrict__ Xkv,
    const __bf16* __restrict__ WT,
    const float* __restrict__ biasQ, const float* __restrict__ biasK,
    const float* __restrict__ biasV,
    float* __restrict__ outf, __bf16* __restrict__ qh, __bf16* __restrict__ kh,
    __bf16* __restrict__ vt,
    const float* __restrict__ scale_q, const float* __restrict__ scale_k,
    const int* __restrict__ qpos, const int* __restrict__ kpos,
    const float2* __restrict__ rtab, int M, int Ntot, int K) {
    __shared__ __bf16 Ab[2][128 * 32];
    __shared__ __bf16 Bb[2][128 * 32];

    const int tid = threadIdx.x;
    const int lane = tid & 63, widx = tid >> 6;
    const int lo = lane & 15, hi = lane >> 4;
    const int wm = widx >> 1, wn = widx & 1;

    // bijective XCD swizzle (gridDim.x % 8 == 0)
    const int nwg = gridDim.x;
    const int q8 = nwg >> 3;
    int bid = blockIdx.x;
    int swz = (bid & 7) * q8 + (bid >> 3);
    const int ntn = Ntot >> 7;
    const int m0 = (swz / ntn) << 7;
    const int nt = swz % ntn;
    const int n0g = nt << 7;                       // row base in WT
    const int seg = (MODE == 3) ? (nt >> 2) : 0;   // 0:Q 1:K 2:V
    const __bf16* X = (MODE == 3 && seg > 0) ? Xkv : Xq;

    const int srow = tid >> 2;
    const int sslot = tid & 3;

    f32x4 acc[4][4] = {};

    auto stage = [&](int kc, int bufi) {
#pragma unroll
        for (int i = 0; i < 2; i++) {
            int row = i * 64 + srow;
            int cs = sslot ^ ((row >> 1) & 3);
            gload_lds16(X + (size_t)(m0 + row) * K + kc + cs * 8,
                        &Ab[bufi][(i * 64 + widx * 16) * 32]);
        }
#pragma unroll
        for (int i = 0; i < 2; i++) {
            int row = i * 64 + srow;
            int cs = sslot ^ ((row >> 1) & 3);
            gload_lds16(WT + (size_t)(n0g + row) * K + kc + cs * 8,
                        &Bb[bufi][(i * 64 + widx * 16) * 32]);
        }
    };

    const int nks = K >> 5;
    stage(0, 0);
    __syncthreads();
    int cur = 0;

    for (int ks = 0; ks < nks; ks++) {
        if (ks + 1 < nks) stage((ks + 1) << 5, cur ^ 1);

        bf16x8 a[4], bvec[4];
#pragma unroll
        for (int mf = 0; mf < 4; mf++) {
            int R = wm * 64 + mf * 16 + lo;
            a[mf] = *reinterpret_cast<const bf16x8*>(&Ab[cur][R * 32 + ((hi ^ ((R >> 1) & 3)) << 3)]);
        }
#pragma unroll
        for (int nf = 0; nf < 4; nf++) {
            int R = wn * 64 + nf * 16 + lo;
            bvec[nf] = *reinterpret_cast<const bf16x8*>(&Bb[cur][R * 32 + ((hi ^ ((R >> 1) & 3)) << 3)]);
        }
#pragma unroll
        for (int mf = 0; mf < 4; mf++)
#pragma unroll
            for (int nf = 0; nf < 4; nf++)
                acc[mf][nf] = __builtin_amdgcn_mfma_f32_16x16x32_bf16(a[mf], bvec[nf], acc[mf][nf], 0, 0, 0);

        __syncthreads();
        cur ^= 1;
    }

    const int mrow0 = m0 + wm * 64;

    if (MODE == 0) {
        const int ncol0 = n0g + wn * 64;
        float bs[4];
#pragma unroll
        for (int nf = 0; nf < 4; nf++) bs[nf] = biasQ[ncol0 + nf * 16 + lo];
#pragma unroll
        for (int mf = 0; mf < 4; mf++)
#pragma unroll
            for (int nf = 0; nf < 4; nf++)
#pragma unroll
                for (int r = 0; r < 4; r++) {
                    int row = mrow0 + mf * 16 + hi * 4 + r;
                    outf[(size_t)row * Ntot + ncol0 + nf * 16 + lo] = acc[mf][nf][r] + bs[nf];
                }
    } else {
        const int ncol0 = ((nt & 3) << 7) + wn * 64;   // within 512-wide segment
        const int h = ncol0 >> 6;
        const float* bias = (seg == 0) ? biasQ : (seg == 1) ? biasK : biasV;
        float bs[4];
#pragma unroll
        for (int nf = 0; nf < 4; nf++) bs[nf] = bias[ncol0 + nf * 16 + lo];

        if (seg < 2) {
            const float* scale = seg ? scale_k : scale_q;
            const int* pos = seg ? kpos : qpos;
            __bf16* dst0 = seg ? kh : qh;
            const float qmul = seg ? 1.0f : QSCALE;
            float sc4[4];
#pragma unroll
            for (int nf = 0; nf < 4; nf++) sc4[nf] = (1.0f + scale[nf * 16 + lo]) * qmul;
#pragma unroll
            for (int mf = 0; mf < 4; mf++) {
#pragma unroll
                for (int r = 0; r < 4; r++) {
                    int row = mrow0 + mf * 16 + hi * 4 + r;
                    float y0 = acc[mf][0][r] + bs[0];
                    float y1 = acc[mf][1][r] + bs[1];
                    float y2 = acc[mf][2][r] + bs[2];
                    float y3 = acc[mf][3][r] + bs[3];
                    float ps = y0 * y0 + y1 * y1 + y2 * y2 + y3 * y3;
#pragma unroll
                    for (int off = 1; off < 16; off <<= 1) ps += __shfl_xor(ps, off);
                    float rmsf = rsqrtf(ps * (1.0f / 64.0f) + 1e-6f);
                    int p = pos[row];
                    float2 c0 = rtab[p * 32 + lo];
                    float2 c1 = rtab[p * 32 + 16 + lo];
                    float z0 = y0 * rmsf * sc4[0];
                    float z1 = y1 * rmsf * sc4[1];
                    float z2 = y2 * rmsf * sc4[2];
                    float z3 = y3 * rmsf * sc4[3];
                    int b = row >> 11, t = row & (T_ - 1);
                    __bf16* dst = dst0 + ((size_t)(b * H_ + h) * T_ + t) * 64;
                    dst[lo]      = (__bf16)(z0 * c0.x - z2 * c0.y);
                    dst[16 + lo] = (__bf16)(z1 * c1.x - z3 * c1.y);
                    dst[32 + lo] = (__bf16)(z2 * c0.x + z0 * c0.y);
                    dst[48 + lo] = (__bf16)(z3 * c1.x + z1 * c1.y);
                }
            }
        } else {
#pragma unroll
            for (int mf = 0; mf < 4; mf++) {
                int row0 = mrow0 + mf * 16 + hi * 4;
                int b = row0 >> 11, t0 = row0 & (T_ - 1);
#pragma unroll
                for (int nf = 0; nf < 4; nf++) {
                    int d = nf * 16 + lo;
                    bf16x4 pk = { (__bf16)(acc[mf][nf][0] + bs[nf]), (__bf16)(acc[mf][nf][1] + bs[nf]),
                                  (__bf16)(acc[mf][nf][2] + bs[nf]), (__bf16)(acc[mf][nf][3] + bs[nf]) };
                    *reinterpret_cast<bf16x4*>(vt + ((size_t)(b * H_ + h) * 64 + d) * T_ + t0) = pk;
                }
            }
        }
    }
}

// ---------------- causal flash attention: 8-wave blocks, 128-row strips ----------------
// qh (pre-scaled by QSCALE*RMSNorm), kh: bf16 [B*H][T][64]; vt: bf16 [B*H][64][T].
// Grid (x=bh 32, y=strip 16), sid = 15-blockIdx.y (longest first). Block = 8 waves,
// each wave owns 16 q rows; all share one staged 64-row K/V tile (dbuf LDS).
// One global_load_lds sweep (512 thr x 16B) stages a full 8KB tile.
// Swapped QK^T: lane holds S[q=lo][kv=16f+4hi+r]; softmax in exp2 units; defer-max.
__global__ __launch_bounds__(512, 6) void attn_kernel(const __bf16* __restrict__ qh,
                                                      const __bf16* __restrict__ kh,
                                                      const __bf16* __restrict__ vt,
                                                      __bf16* __restrict__ attn) {
    __shared__ __bf16 kbuf[2][64 * 64];
    __shared__ __bf16 vbuf[2][64 * 64];
    __shared__ __bf16 plds[8][16][72];

    const int lane = threadIdx.x & 63, widx = threadIdx.x >> 6;
    const int lo = lane & 15, hi = lane >> 4;
    const int bh = blockIdx.x;
    const int sid = 15 - blockIdx.y;          // longest strips dispatched first
    const int ntiles = 2 * sid + 2;
    const int qb = sid * 128 + widx * 16;
    const __bf16* Qg = qh + (size_t)bh * T_ * 64;
    const __bf16* Kg = kh + (size_t)bh * T_ * 64;
    const __bf16* Vg = vt + (size_t)bh * 64 * T_;
    const int b = bh >> 3, h = bh & 7;

    // staging: 512 threads x 16B = one full 64x64 bf16 tile per call.
    // row = widx*8 + (lane>>3); within-row 16B slot = lane&7 holds logical
    // chunk schunk = slot ^ (row&7) (inverse-swizzled source, linear dest).
    const int srow = widx * 8 + (lane >> 3);
    const int schunk = (lane & 7) ^ (srow & 7);

    bf16x8 qa[2];
#pragma unroll
    for (int c = 0; c < 2; c++)
        qa[c] = *reinterpret_cast<const bf16x8*>(Qg + (size_t)(qb + lo) * 64 + c * 32 + hi * 8);

    f32x4 o[4] = {};
    float m = -1e30f, l = 0.0f;

    auto stage = [&](int tile, int bufi) {
        const int kvb0 = tile * 64;
        gload_lds16(Kg + (size_t)(kvb0 + srow) * 64 + schunk * 8,
                    &kbuf[bufi][widx * 8 * 64]);
        gload_lds16(Vg + (size_t)srow * T_ + kvb0 + schunk * 8,
                    &vbuf[bufi][widx * 8 * 64]);
    };

    stage(0, 0);
    __syncthreads();
    int cur = 0;

    for (int j = 0; j < ntiles; ++j) {
        if (j + 1 < ntiles) stage(j + 1, cur ^ 1);

        const int dj = j - 2 * sid;                 // >=0 only for last two tiles
        const bool active = !(dj == 1 && widx < 4); // fully-masked waves skip
        if (active) {
            // ---- S^T = K x Q^T : s[f][r] = S[q=lo][kv=j*64+16f+4hi+r] ----
            f32x4 s[4] = {};
            __builtin_amdgcn_s_setprio(1);
#pragma unroll
            for (int c = 0; c < 2; c++) {
#pragma unroll
                for (int f = 0; f < 4; f++) {
                    int R = f * 16 + lo;
                    int C = c * 4 + hi;
                    bf16x8 kb = *reinterpret_cast<const bf16x8*>(
                        &kbuf[cur][R * 64 + ((C ^ (lo & 7)) << 3)]);
                    s[f] = __builtin_amdgcn_mfma_f32_16x16x32_bf16(kb, qa[c], s[f], 0, 0, 0);
                }
            }
            __builtin_amdgcn_s_setprio(0);

            // ---- mask (diag tiles only) + in-lane max ----
            const bool diag = (dj == 0 && widx < 4) || (dj == 1 && widx >= 4);
            float pm = -1e30f;
#pragma unroll
            for (int f = 0; f < 4; f++)
#pragma unroll
                for (int r = 0; r < 4; r++) {
                    float v = s[f][r];
                    if (diag && (j * 64 + f * 16 + hi * 4 + r > qb + lo)) v = -1e30f;
                    s[f][r] = v;
                    pm = fmaxf(pm, v);
                }
            pm = fmaxf(pm, __shfl_xor(pm, 16));
            pm = fmaxf(pm, __shfl_xor(pm, 32));

            // ---- defer-max (T13) ----
            if (!__all(pm <= m + DEFER_THR)) {
                float mn = fmaxf(m, pm);
                float alpha = exp2f(m - mn);
                l *= alpha;
#pragma unroll
                for (int n = 0; n < 4; n++)
#pragma unroll
                    for (int r = 0; r < 4; r++) o[n][r] *= alpha;
                m = mn;
            }

            // ---- exp2 + in-lane sum + P pack ----
            float ps = 0.0f;
            bf16x4 pk[4];
#pragma unroll
            for (int f = 0; f < 4; f++) {
#pragma unroll
                for (int r = 0; r < 4; r++) {
                    float e = exp2f(s[f][r] - m);
                    ps += e;
                    pk[f][r] = (__bf16)e;
                }
            }
            ps += __shfl_xor(ps, 16);
            ps += __shfl_xor(ps, 32);
            l += ps;

            // ---- P -> LDS (per-wave) -> B-fragments ----
#pragma unroll
            for (int f = 0; f < 4; f++)
                *reinterpret_cast<bf16x4*>(&plds[widx][lo][f * 16 + hi * 4]) = pk[f];
            bf16x8 pa0 = *reinterpret_cast<const bf16x8*>(&plds[widx][lo][hi * 8]);
            bf16x8 pa1 = *reinterpret_cast<const bf16x8*>(&plds[widx][lo][32 + hi * 8]);

            // ---- O^T += V^T x P^T ----
            __builtin_amdgcn_s_setprio(1);
#pragma unroll
            for (int n = 0; n < 4; n++) {
#pragma unroll
                for (int c = 0; c < 2; c++) {
                    int R = n * 16 + lo;
                    int C = c * 4 + hi;
                    bf16x8 vb = *reinterpret_cast<const bf16x8*>(
                        &vbuf[cur][R * 64 + ((C ^ (lo & 7)) << 3)]);
                    o[n] = __builtin_amdgcn_mfma_f32_16x16x32_bf16(vb, c ? pa1 : pa0, o[n], 0, 0, 0);
                }
            }
            __builtin_amdgcn_s_setprio(0);
        }

        __syncthreads();
        cur ^= 1;
    }

    const float inv = 1.0f / l;
    const int qrow = qb + lo;
#pragma unroll
    for (int n = 0; n < 4; n++) {
        bf16x4 pko = { (__bf16)(o[n][0] * inv), (__bf16)(o[n][1] * inv),
                       (__bf16)(o[n][2] * inv), (__bf16)(o[n][3] * inv) };
        *reinterpret_cast<bf16x4*>(attn + ((size_t)b * T_ + qrow) * D_ + h * 64 + n * 16 + hi * 4) = pko;
    }
}

extern "C" void kernel_launch(void* const* d_in, const int* in_sizes, int n_in,
                              void* d_out, int out_size, void* d_ws, size_t ws_size,
                              hipStream_t stream) {
    const float* q  = (const float*)d_in[0];
    const float* kv = (const float*)d_in[1];
    const int* qpos = (const int*)d_in[3];
    const int* kpos = (const int*)d_in[4];
    const float* wq = (const float*)d_in[5];
    const float* bq = (const float*)d_in[6];
    const float* wk = (const float*)d_in[7];
    const float* bk = (const float*)d_in[8];
    const float* wv = (const float*)d_in[9];
    const float* bv = (const float*)d_in[10];
    const float* scale_q = (const float*)d_in[11];
    const float* scale_k = (const float*)d_in[12];
    const float* wo = (const float*)d_in[13];
    const float* bo = (const float*)d_in[14];
    float* out = (float*)d_out;

    char* ws = (char*)d_ws;
    size_t off = 0;
    auto alloc = [&](size_t bytes) {
        void* p = ws + off;
        off += (bytes + 255) & ~(size_t)255;
        return p;
    };
    const size_t MD = (size_t)B_ * T_ * D_;
    __bf16* qb16   = (__bf16*)alloc(MD * 2);
    __bf16* kvb16  = (__bf16*)alloc(MD * 2);
    __bf16* wqkvT  = (__bf16*)alloc((size_t)3 * D_ * D_ * 2);
    __bf16* woT    = (__bf16*)alloc((size_t)D_ * D_ * 2);
    __bf16* qh  = (__bf16*)alloc(MD * 2);
    __bf16* kh  = (__bf16*)alloc(MD * 2);
    __bf16* vt  = (__bf16*)alloc(MD * 2);
    float2* rtab = (float2*)alloc((size_t)T_ * 32 * sizeof(float2));
    __bf16* attn = qb16;  // reuse: qb16 dead after QKV GEMM

    cast2_kernel<<<2048, 256, 0, stream>>>(q, kv, qb16, kvb16, (int)(MD / 4));
    transpose_w4_kernel<<<dim3(16, 16, 4), 256, 0, stream>>>(wq, wk, wv, wo, wqkvT, woT);
    rope_table_kernel<<<(T_ * 32) / 256, 256, 0, stream>>>(rtab);

    const int M = B_ * T_;
    // fused QKV projection + RMSNorm/RoPE/V-transpose epilogues: N=1536 -> 768 blocks
    gemm_tile_kernel<3><<<(M / 128) * (3 * D_ / 128), 256, 0, stream>>>(
        qb16, kvb16, wqkvT, bq, bk, bv, nullptr, qh, kh, vt,
        scale_q, scale_k, qpos, kpos, rtab, M, 3 * D_, D_);
    // attention: grid (bh, strip), strips of one bh pinned to one XCD by dispatch
    attn_kernel<<<dim3(B_ * H_, 16), 512, 0, stream>>>(qh, kh, vt, attn);
    // output projection
    gemm_tile_kernel<0><<<(M / 128) * (D_ / 128), 256, 0, stream>>>(
        attn, nullptr, woT, bo, nullptr, nullptr, out, nullptr, nullptr, nullptr,
        nullptr, nullptr, nullptr, nullptr, nullptr, M, D_, D_);
}

// Round 7
// 89.356 us; speedup vs baseline: 1.3733x; 1.2360x over previous
//
#include <hip/hip_runtime.h>
#include <hip/hip_bf16.h>
#include <cstdint>

#define B_ 4
#define T_ 2048
#define D_ 512
#define H_ 8

typedef __bf16 bf16x8 __attribute__((ext_vector_type(8)));
typedef __bf16 bf16x4 __attribute__((ext_vector_type(4)));
typedef float f32x4 __attribute__((ext_vector_type(4)));

// 0.125 (1/sqrt(Dh)) * log2(e), folded into Q so softmax uses exp2 directly
#define QSCALE 0.18033688011112042f
// Fixed softmax shift: |S_exp2| <= ||q||*||k||*0.125*log2(e) ~= 13.4 < 16 (Cauchy-Schwarz
// with RMSNorm'd rows; RoPE is norm-preserving). exp2(s-16) in [2^-32, 1]: no overflow,
// no max tracking needed. Folded into the QK MFMA accumulator init.
#define MSHIFT 16.0f

__device__ inline void gload_lds16(const void* g, void* l) {
    __builtin_amdgcn_global_load_lds(
        (const __attribute__((address_space(1))) void*)g,
        (__attribute__((address_space(3))) void*)l, 16, 0, 0);
}

// ---------------- cast fp32 -> bf16 for q and kv in one launch ----------------
__global__ void cast2_kernel(const float* __restrict__ qf, const float* __restrict__ kvf,
                             __bf16* __restrict__ qb, __bf16* __restrict__ kvb, int n4) {
    int stride = gridDim.x * blockDim.x;
    for (int i = blockIdx.x * blockDim.x + threadIdx.x; i < 2 * n4; i += stride) {
        const float* src = (i < n4) ? qf : kvf;
        __bf16* dst = (i < n4) ? qb : kvb;
        int j = (i < n4) ? i : i - n4;
        float4 v = reinterpret_cast<const float4*>(src)[j];
        bf16x4 o = { (__bf16)v.x, (__bf16)v.y, (__bf16)v.z, (__bf16)v.w };
        reinterpret_cast<bf16x4*>(dst)[j] = o;
    }
}

// ---------------- transpose all 4 weights (z selects) ----------------
__global__ void transpose_w4_kernel(const float* __restrict__ wq, const float* __restrict__ wk,
                                    const float* __restrict__ wv, const float* __restrict__ wo,
                                    __bf16* __restrict__ wqkvT, __bf16* __restrict__ woT) {
    __shared__ float tile[32][33];
    int z = blockIdx.z;
    const float* in = (z == 0) ? wq : (z == 1) ? wk : (z == 2) ? wv : wo;
    __bf16* out = (z < 3) ? wqkvT + (size_t)z * D_ * D_ : woT;
    int tx = threadIdx.x & 31, ty = threadIdx.x >> 5;
    int r0 = blockIdx.y * 32, c0 = blockIdx.x * 32;
#pragma unroll
    for (int i = 0; i < 4; i++)
        tile[ty + i * 8][tx] = in[(size_t)(r0 + ty + i * 8) * D_ + c0 + tx];
    __syncthreads();
#pragma unroll
    for (int i = 0; i < 4; i++)
        out[(size_t)(c0 + ty + i * 8) * D_ + r0 + tx] = (__bf16)tile[tx][ty + i * 8];
}

// ---------------- RoPE cos/sin table ----------------
__global__ void rope_table_kernel(float2* __restrict__ tab) {
    int i = blockIdx.x * 256 + threadIdx.x;     // T*32 entries
    int p = i >> 5, d2 = i & 31;
    float inv_ts = exp2f((float)d2 * (-13.28771237954945f / 32.0f));
    float ang = (float)p * inv_ts;
    float sv, cv;
    __sincosf(ang, &sv, &cv);
    tab[i] = make_float2(cv, sv);
}

// ---------------- tiled GEMM: 128x128 tile, BK=32, double-buffered LDS ----------------
// MODE 0: out = X @ woT^T + bo -> fp32 [M][512]
// MODE 3: fused QKV: WT is [1536][512]; segment 0/1 -> RMSNorm+RoPE bf16 heads
//         (segment 0 additionally folds QSCALE), segment 2 -> V^T bf16 [B*H][64][T]
template<int MODE>
__global__ __launch_bounds__(256, 2) void gemm_tile_kernel(
    const __bf16* __restrict__ Xq, const __bf16* __restrict__ Xkv,
    const __bf16* __restrict__ WT,
    const float* __restrict__ biasQ, const float* __restrict__ biasK,
    const float* __restrict__ biasV,
    float* __restrict__ outf, __bf16* __restrict__ qh, __bf16* __restrict__ kh,
    __bf16* __restrict__ vt,
    const float* __restrict__ scale_q, const float* __restrict__ scale_k,
    const int* __restrict__ qpos, const int* __restrict__ kpos,
    const float2* __restrict__ rtab, int M, int Ntot, int K) {
    __shared__ __bf16 Ab[2][128 * 32];
    __shared__ __bf16 Bb[2][128 * 32];

    const int tid = threadIdx.x;
    const int lane = tid & 63, widx = tid >> 6;
    const int lo = lane & 15, hi = lane >> 4;
    const int wm = widx >> 1, wn = widx & 1;

    // bijective XCD swizzle (gridDim.x % 8 == 0)
    const int nwg = gridDim.x;
    const int q8 = nwg >> 3;
    int bid = blockIdx.x;
    int swz = (bid & 7) * q8 + (bid >> 3);
    const int ntn = Ntot >> 7;
    const int m0 = (swz / ntn) << 7;
    const int nt = swz % ntn;
    const int n0g = nt << 7;                       // row base in WT
    const int seg = (MODE == 3) ? (nt >> 2) : 0;   // 0:Q 1:K 2:V
    const __bf16* X = (MODE == 3 && seg > 0) ? Xkv : Xq;

    const int srow = tid >> 2;
    const int sslot = tid & 3;

    f32x4 acc[4][4] = {};

    auto stage = [&](int kc, int bufi) {
#pragma unroll
        for (int i = 0; i < 2; i++) {
            int row = i * 64 + srow;
            int cs = sslot ^ ((row >> 1) & 3);
            gload_lds16(X + (size_t)(m0 + row) * K + kc + cs * 8,
                        &Ab[bufi][(i * 64 + widx * 16) * 32]);
        }
#pragma unroll
        for (int i = 0; i < 2; i++) {
            int row = i * 64 + srow;
            int cs = sslot ^ ((row >> 1) & 3);
            gload_lds16(WT + (size_t)(n0g + row) * K + kc + cs * 8,
                        &Bb[bufi][(i * 64 + widx * 16) * 32]);
        }
    };

    const int nks = K >> 5;
    stage(0, 0);
    __syncthreads();
    int cur = 0;

    for (int ks = 0; ks < nks; ks++) {
        if (ks + 1 < nks) stage((ks + 1) << 5, cur ^ 1);

        bf16x8 a[4], bvec[4];
#pragma unroll
        for (int mf = 0; mf < 4; mf++) {
            int R = wm * 64 + mf * 16 + lo;
            a[mf] = *reinterpret_cast<const bf16x8*>(&Ab[cur][R * 32 + ((hi ^ ((R >> 1) & 3)) << 3)]);
        }
#pragma unroll
        for (int nf = 0; nf < 4; nf++) {
            int R = wn * 64 + nf * 16 + lo;
            bvec[nf] = *reinterpret_cast<const bf16x8*>(&Bb[cur][R * 32 + ((hi ^ ((R >> 1) & 3)) << 3)]);
        }
#pragma unroll
        for (int mf = 0; mf < 4; mf++)
#pragma unroll
            for (int nf = 0; nf < 4; nf++)
                acc[mf][nf] = __builtin_amdgcn_mfma_f32_16x16x32_bf16(a[mf], bvec[nf], acc[mf][nf], 0, 0, 0);

        __syncthreads();
        cur ^= 1;
    }

    const int mrow0 = m0 + wm * 64;

    if (MODE == 0) {
        const int ncol0 = n0g + wn * 64;
        float bs[4];
#pragma unroll
        for (int nf = 0; nf < 4; nf++) bs[nf] = biasQ[ncol0 + nf * 16 + lo];
#pragma unroll
        for (int mf = 0; mf < 4; mf++)
#pragma unroll
            for (int nf = 0; nf < 4; nf++)
#pragma unroll
                for (int r = 0; r < 4; r++) {
                    int row = mrow0 + mf * 16 + hi * 4 + r;
                    outf[(size_t)row * Ntot + ncol0 + nf * 16 + lo] = acc[mf][nf][r] + bs[nf];
                }
    } else {
        const int ncol0 = ((nt & 3) << 7) + wn * 64;   // within 512-wide segment
        const int h = ncol0 >> 6;
        const float* bias = (seg == 0) ? biasQ : (seg == 1) ? biasK : biasV;
        float bs[4];
#pragma unroll
        for (int nf = 0; nf < 4; nf++) bs[nf] = bias[ncol0 + nf * 16 + lo];

        if (seg < 2) {
            const float* scale = seg ? scale_k : scale_q;
            const int* pos = seg ? kpos : qpos;
            __bf16* dst0 = seg ? kh : qh;
            const float qmul = seg ? 1.0f : QSCALE;
            float sc4[4];
#pragma unroll
            for (int nf = 0; nf < 4; nf++) sc4[nf] = (1.0f + scale[nf * 16 + lo]) * qmul;
#pragma unroll
            for (int mf = 0; mf < 4; mf++) {
#pragma unroll
                for (int r = 0; r < 4; r++) {
                    int row = mrow0 + mf * 16 + hi * 4 + r;
                    float y0 = acc[mf][0][r] + bs[0];
                    float y1 = acc[mf][1][r] + bs[1];
                    float y2 = acc[mf][2][r] + bs[2];
                    float y3 = acc[mf][3][r] + bs[3];
                    float ps = y0 * y0 + y1 * y1 + y2 * y2 + y3 * y3;
#pragma unroll
                    for (int off = 1; off < 16; off <<= 1) ps += __shfl_xor(ps, off);
                    float rmsf = rsqrtf(ps * (1.0f / 64.0f) + 1e-6f);
                    int p = pos[row];
                    float2 c0 = rtab[p * 32 + lo];
                    float2 c1 = rtab[p * 32 + 16 + lo];
                    float z0 = y0 * rmsf * sc4[0];
                    float z1 = y1 * rmsf * sc4[1];
                    float z2 = y2 * rmsf * sc4[2];
                    float z3 = y3 * rmsf * sc4[3];
                    int b = row >> 11, t = row & (T_ - 1);
                    __bf16* dst = dst0 + ((size_t)(b * H_ + h) * T_ + t) * 64;
                    dst[lo]      = (__bf16)(z0 * c0.x - z2 * c0.y);
                    dst[16 + lo] = (__bf16)(z1 * c1.x - z3 * c1.y);
                    dst[32 + lo] = (__bf16)(z2 * c0.x + z0 * c0.y);
                    dst[48 + lo] = (__bf16)(z3 * c1.x + z1 * c1.y);
                }
            }
        } else {
#pragma unroll
            for (int mf = 0; mf < 4; mf++) {
                int row0 = mrow0 + mf * 16 + hi * 4;
                int b = row0 >> 11, t0 = row0 & (T_ - 1);
#pragma unroll
                for (int nf = 0; nf < 4; nf++) {
                    int d = nf * 16 + lo;
                    bf16x4 pk = { (__bf16)(acc[mf][nf][0] + bs[nf]), (__bf16)(acc[mf][nf][1] + bs[nf]),
                                  (__bf16)(acc[mf][nf][2] + bs[nf]), (__bf16)(acc[mf][nf][3] + bs[nf]) };
                    *reinterpret_cast<bf16x4*>(vt + ((size_t)(b * H_ + h) * 64 + d) * T_ + t0) = pk;
                }
            }
        }
    }
}

// ---------------- causal flash attention: fixed-shift softmax, 64-row strips ----------------
// qh (pre-scaled by QSCALE*RMSNorm), kh: bf16 [B*H][T][64]; vt: bf16 [B*H][64][T].
// Grid (x=bh 32, y=strip 32), sid = 31-blockIdx.y (longest first). Block = 4 waves,
// each wave owns 16 q rows of the 64-row strip; K/V 64-row tiles dbuf-staged in LDS.
// Swapped QK^T: lane holds S[q=lo][kv=16f+4hi+r]. Softmax uses FIXED shift -16
// (folded into MFMA C-init; Cauchy-Schwarz bound, see MSHIFT) -> no max tracking,
// no rescale, no cross-lane max: per tile just 16 exp2 + sum.
__global__ __launch_bounds__(256, 3) void attn_kernel(const __bf16* __restrict__ qh,
                                                      const __bf16* __restrict__ kh,
                                                      const __bf16* __restrict__ vt,
                                                      __bf16* __restrict__ attn) {
    __shared__ __bf16 kbuf[2][64 * 64];
    __shared__ __bf16 vbuf[2][64 * 64];
    __shared__ __bf16 plds[4][16][72];

    const int lane = threadIdx.x & 63, widx = threadIdx.x >> 6;
    const int lo = lane & 15, hi = lane >> 4;
    const int bh = blockIdx.x;
    const int sid = 31 - blockIdx.y;          // longest strips dispatched first
    const int ntiles = sid + 1;
    const int qb = sid * 64 + widx * 16;
    const __bf16* Qg = qh + (size_t)bh * T_ * 64;
    const __bf16* Kg = kh + (size_t)bh * T_ * 64;
    const __bf16* Vg = vt + (size_t)bh * 64 * T_;
    const int b = bh >> 3, h = bh & 7;

    const int srow = lane >> 3;
    const int sslot = lane & 7;
    const int schunk = sslot ^ srow;

    bf16x8 qa[2];
#pragma unroll
    for (int c = 0; c < 2; c++)
        qa[c] = *reinterpret_cast<const bf16x8*>(Qg + (size_t)(qb + lo) * 64 + c * 32 + hi * 8);

    f32x4 o[4] = {};
    float l = 0.0f;
    const f32x4 minit = { -MSHIFT, -MSHIFT, -MSHIFT, -MSHIFT };

    auto stage = [&](int tile, int bufi) {
        const int kvb0 = tile * 64;
#pragma unroll
        for (int i = 0; i < 2; i++) {
            int r = widx * 16 + i * 8 + srow;
            gload_lds16(Kg + (size_t)(kvb0 + r) * 64 + schunk * 8,
                        &kbuf[bufi][(widx * 16 + i * 8) * 64]);
        }
#pragma unroll
        for (int i = 0; i < 2; i++) {
            int r = widx * 16 + i * 8 + srow;
            gload_lds16(Vg + (size_t)r * T_ + kvb0 + schunk * 8,
                        &vbuf[bufi][(widx * 16 + i * 8) * 64]);
        }
    };

    stage(0, 0);
    __syncthreads();
    int cur = 0;

    for (int j = 0; j < ntiles; ++j) {
        if (j + 1 < ntiles) stage(j + 1, cur ^ 1);

        // ---- S^T = K x Q^T (C-init = -MSHIFT): s[f][r] = S[q=lo][kv=16f+4hi+r] - 16 ----
        f32x4 s[4] = { minit, minit, minit, minit };
        __builtin_amdgcn_s_setprio(1);
#pragma unroll
        for (int c = 0; c < 2; c++) {
#pragma unroll
            for (int f = 0; f < 4; f++) {
                int R = f * 16 + lo;
                int C = c * 4 + hi;
                bf16x8 kb = *reinterpret_cast<const bf16x8*>(
                    &kbuf[cur][R * 64 + ((C ^ (lo & 7)) << 3)]);
                s[f] = __builtin_amdgcn_mfma_f32_16x16x32_bf16(kb, qa[c], s[f], 0, 0, 0);
            }
        }
        __builtin_amdgcn_s_setprio(0);

        // ---- mask (diag tile only) ----
        if (j == ntiles - 1) {
#pragma unroll
            for (int f = 0; f < 4; f++)
#pragma unroll
                for (int r = 0; r < 4; r++)
                    if (f * 16 + hi * 4 + r > widx * 16 + lo) s[f][r] = -1e30f;
        }

        // ---- P = exp2(s), in-lane + cross-half sum ----
        float ps = 0.0f;
        bf16x4 pk[4];
#pragma unroll
        for (int f = 0; f < 4; f++) {
#pragma unroll
            for (int r = 0; r < 4; r++) {
                float e = __builtin_amdgcn_exp2f(s[f][r]);
                ps += e;
                pk[f][r] = (__bf16)e;
            }
        }
        ps += __shfl_xor(ps, 16);
        ps += __shfl_xor(ps, 32);
        l += ps;

        // ---- P -> LDS (per-wave) -> B-fragments ----
#pragma unroll
        for (int f = 0; f < 4; f++)
            *reinterpret_cast<bf16x4*>(&plds[widx][lo][f * 16 + hi * 4]) = pk[f];
        bf16x8 pa0 = *reinterpret_cast<const bf16x8*>(&plds[widx][lo][hi * 8]);
        bf16x8 pa1 = *reinterpret_cast<const bf16x8*>(&plds[widx][lo][32 + hi * 8]);

        // ---- O^T += V^T x P^T ----
        __builtin_amdgcn_s_setprio(1);
#pragma unroll
        for (int n = 0; n < 4; n++) {
#pragma unroll
            for (int c = 0; c < 2; c++) {
                int R = n * 16 + lo;
                int C = c * 4 + hi;
                bf16x8 vb = *reinterpret_cast<const bf16x8*>(
                    &vbuf[cur][R * 64 + ((C ^ (lo & 7)) << 3)]);
                o[n] = __builtin_amdgcn_mfma_f32_16x16x32_bf16(vb, c ? pa1 : pa0, o[n], 0, 0, 0);
            }
        }
        __builtin_amdgcn_s_setprio(0);

        __syncthreads();
        cur ^= 1;
    }

    const float inv = 1.0f / l;
    const int qrow = qb + lo;
#pragma unroll
    for (int n = 0; n < 4; n++) {
        bf16x4 pko = { (__bf16)(o[n][0] * inv), (__bf16)(o[n][1] * inv),
                       (__bf16)(o[n][2] * inv), (__bf16)(o[n][3] * inv) };
        *reinterpret_cast<bf16x4*>(attn + ((size_t)b * T_ + qrow) * D_ + h * 64 + n * 16 + hi * 4) = pko;
    }
}

extern "C" void kernel_launch(void* const* d_in, const int* in_sizes, int n_in,
                              void* d_out, int out_size, void* d_ws, size_t ws_size,
                              hipStream_t stream) {
    const float* q  = (const float*)d_in[0];
    const float* kv = (const float*)d_in[1];
    const int* qpos = (const int*)d_in[3];
    const int* kpos = (const int*)d_in[4];
    const float* wq = (const float*)d_in[5];
    const float* bq = (const float*)d_in[6];
    const float* wk = (const float*)d_in[7];
    const float* bk = (const float*)d_in[8];
    const float* wv = (const float*)d_in[9];
    const float* bv = (const float*)d_in[10];
    const float* scale_q = (const float*)d_in[11];
    const float* scale_k = (const float*)d_in[12];
    const float* wo = (const float*)d_in[13];
    const float* bo = (const float*)d_in[14];
    float* out = (float*)d_out;

    char* ws = (char*)d_ws;
    size_t off = 0;
    auto alloc = [&](size_t bytes) {
        void* p = ws + off;
        off += (bytes + 255) & ~(size_t)255;
        return p;
    };
    const size_t MD = (size_t)B_ * T_ * D_;
    __bf16* qb16   = (__bf16*)alloc(MD * 2);
    __bf16* kvb16  = (__bf16*)alloc(MD * 2);
    __bf16* wqkvT  = (__bf16*)alloc((size_t)3 * D_ * D_ * 2);
    __bf16* woT    = (__bf16*)alloc((size_t)D_ * D_ * 2);
    __bf16* qh  = (__bf16*)alloc(MD * 2);
    __bf16* kh  = (__bf16*)alloc(MD * 2);
    __bf16* vt  = (__bf16*)alloc(MD * 2);
    float2* rtab = (float2*)alloc((size_t)T_ * 32 * sizeof(float2));
    __bf16* attn = qb16;  // reuse: qb16 dead after QKV GEMM

    cast2_kernel<<<2048, 256, 0, stream>>>(q, kv, qb16, kvb16, (int)(MD / 4));
    transpose_w4_kernel<<<dim3(16, 16, 4), 256, 0, stream>>>(wq, wk, wv, wo, wqkvT, woT);
    rope_table_kernel<<<(T_ * 32) / 256, 256, 0, stream>>>(rtab);

    const int M = B_ * T_;
    // fused QKV projection + RMSNorm/RoPE/V-transpose epilogues: N=1536 -> 768 blocks
    gemm_tile_kernel<3><<<(M / 128) * (3 * D_ / 128), 256, 0, stream>>>(
        qb16, kvb16, wqkvT, bq, bk, bv, nullptr, qh, kh, vt,
        scale_q, scale_k, qpos, kpos, rtab, M, 3 * D_, D_);
    // attention: grid (bh, strip), longest strips first; 64-row strips
    attn_kernel<<<dim3(B_ * H_, 32), 256, 0, stream>>>(qh, kh, vt, attn);
    // output projection
    gemm_tile_kernel<0><<<(M / 128) * (D_ / 128), 256, 0, stream>>>(
        attn, nullptr, woT, bo, nullptr, nullptr, out, nullptr, nullptr, nullptr,
        nullptr, nullptr, nullptr, nullptr, nullptr, M, D_, D_);
}

// Round 9
// 85.577 us; speedup vs baseline: 1.4340x; 1.0442x over previous
//
#include <hip/hip_runtime.h>
#include <hip/hip_bf16.h>
#include <cstdint>

#define B_ 4
#define T_ 2048
#define D_ 512
#define H_ 8

typedef __bf16 bf16x8 __attribute__((ext_vector_type(8)));
typedef __bf16 bf16x4 __attribute__((ext_vector_type(4)));
typedef float f32x4 __attribute__((ext_vector_type(4)));

// 0.125 (1/sqrt(Dh)) * log2(e), folded into Q so softmax uses exp2 directly
#define QSCALE 0.18033688011112042f
// Fixed softmax shift: |S_exp2| <= ||q||*||k||*0.125*log2(e) ~= 13.4 < 16 (Cauchy-Schwarz
// with RMSNorm'd rows; RoPE is norm-preserving). exp2(s-16) in [2^-32, 1]: no overflow,
// no max tracking needed. Folded into the QK MFMA accumulator init.
#define MSHIFT 16.0f

__device__ inline void gload_lds16(const void* g, void* l) {
    __builtin_amdgcn_global_load_lds(
        (const __attribute__((address_space(1))) void*)g,
        (__attribute__((address_space(3))) void*)l, 16, 0, 0);
}

// ---------------- transpose all 4 weights (z selects) ----------------
__global__ void transpose_w4_kernel(const float* __restrict__ wq, const float* __restrict__ wk,
                                    const float* __restrict__ wv, const float* __restrict__ wo,
                                    __bf16* __restrict__ wqkvT, __bf16* __restrict__ woT) {
    __shared__ float tile[32][33];
    int z = blockIdx.z;
    const float* in = (z == 0) ? wq : (z == 1) ? wk : (z == 2) ? wv : wo;
    __bf16* out = (z < 3) ? wqkvT + (size_t)z * D_ * D_ : woT;
    int tx = threadIdx.x & 31, ty = threadIdx.x >> 5;
    int r0 = blockIdx.y * 32, c0 = blockIdx.x * 32;
#pragma unroll
    for (int i = 0; i < 4; i++)
        tile[ty + i * 8][tx] = in[(size_t)(r0 + ty + i * 8) * D_ + c0 + tx];
    __syncthreads();
#pragma unroll
    for (int i = 0; i < 4; i++)
        out[(size_t)(c0 + ty + i * 8) * D_ + r0 + tx] = (__bf16)tile[tx][ty + i * 8];
}

// ---------------- RoPE cos/sin table ----------------
__global__ void rope_table_kernel(float2* __restrict__ tab) {
    int i = blockIdx.x * 256 + threadIdx.x;     // T*32 entries
    int p = i >> 5, d2 = i & 31;
    float inv_ts = exp2f((float)d2 * (-13.28771237954945f / 32.0f));
    float ang = (float)p * inv_ts;
    float sv, cv;
    __sincosf(ang, &sv, &cv);
    tab[i] = make_float2(cv, sv);
}

// ---------------- tiled GEMM: 128x128 tile, BK=32, double-buffered LDS ----------------
// MODE 0: out = Xbf(bf16) @ woT^T + bo -> fp32 [M][512]; A via global_load_lds.
// MODE 3: fused QKV from FP32 activations (cast folded into A reg-staging):
//         WT is [1536][512]; segment 0/1 -> RMSNorm+RoPE bf16 heads (seg 0 folds
//         QSCALE), segment 2 -> V^T bf16 [B*H][64][T].
// LDS image identical in both modes: phys chunk slot s holds logical chunk
// s ^ ((row>>1)&3); read at (hi ^ ((row>>1)&3)).
template<int MODE>
__global__ __launch_bounds__(256, 2) void gemm_tile_kernel(
    const float* __restrict__ Aq32, const float* __restrict__ Akv32,
    const __bf16* __restrict__ Xbf,
    const __bf16* __restrict__ WT,
    const float* __restrict__ biasQ, const float* __restrict__ biasK,
    const float* __restrict__ biasV,
    float* __restrict__ outf, __bf16* __restrict__ qh, __bf16* __restrict__ kh,
    __bf16* __restrict__ vt,
    const float* __restrict__ scale_q, const float* __restrict__ scale_k,
    const int* __restrict__ qpos, const int* __restrict__ kpos,
    const float2* __restrict__ rtab, int M, int Ntot, int K) {
    __shared__ __bf16 Ab[2][128 * 32];
    __shared__ __bf16 Bb[2][128 * 32];

    const int tid = threadIdx.x;
    const int lane = tid & 63, widx = tid >> 6;
    const int lo = lane & 15, hi = lane >> 4;
    const int wm = widx >> 1, wn = widx & 1;

    // bijective XCD swizzle (gridDim.x % 8 == 0)
    const int nwg = gridDim.x;
    const int q8 = nwg >> 3;
    int bid = blockIdx.x;
    int swz = (bid & 7) * q8 + (bid >> 3);
    const int ntn = Ntot >> 7;
    const int m0 = (swz / ntn) << 7;
    const int nt = swz % ntn;
    const int n0g = nt << 7;                       // row base in WT
    const int seg = (MODE == 3) ? (nt >> 2) : 0;   // 0:Q 1:K 2:V

    const int srow = tid >> 2;
    const int sslot = tid & 3;

    const float* Af32 = (MODE == 3) ? ((seg > 0) ? Akv32 : Aq32) : nullptr;

    f32x4 acc[4][4] = {};
    float4 areg[2][2];

    auto stageB = [&](int kc, int bufi) {
#pragma unroll
        for (int i = 0; i < 2; i++) {
            int row = i * 64 + srow;
            int cs = sslot ^ ((row >> 1) & 3);
            gload_lds16(WT + (size_t)(n0g + row) * K + kc + cs * 8,
                        &Bb[bufi][(i * 64 + widx * 16) * 32]);
        }
    };
    auto stageA_bf = [&](int kc, int bufi) {
#pragma unroll
        for (int i = 0; i < 2; i++) {
            int row = i * 64 + srow;
            int cs = sslot ^ ((row >> 1) & 3);
            gload_lds16(Xbf + (size_t)(m0 + row) * K + kc + cs * 8,
                        &Ab[bufi][(i * 64 + widx * 16) * 32]);
        }
    };
    auto loadA32 = [&](int kc) {
#pragma unroll
        for (int i = 0; i < 2; i++) {
            const float* src = Af32 + (size_t)(m0 + i * 64 + srow) * K + kc + sslot * 8;
            areg[i][0] = *reinterpret_cast<const float4*>(src);
            areg[i][1] = *reinterpret_cast<const float4*>(src + 4);
        }
    };
    auto writeA32 = [&](int bufi) {
#pragma unroll
        for (int i = 0; i < 2; i++) {
            int row = i * 64 + srow;
            bf16x8 v = { (__bf16)areg[i][0].x, (__bf16)areg[i][0].y,
                         (__bf16)areg[i][0].z, (__bf16)areg[i][0].w,
                         (__bf16)areg[i][1].x, (__bf16)areg[i][1].y,
                         (__bf16)areg[i][1].z, (__bf16)areg[i][1].w };
            *reinterpret_cast<bf16x8*>(
                &Ab[bufi][row * 32 + ((sslot ^ ((row >> 1) & 3)) << 3)]) = v;
        }
    };

    const int nks = K >> 5;
    if constexpr (MODE == 3) {
        loadA32(0); stageB(0, 0); writeA32(0);
    } else {
        stageA_bf(0, 0); stageB(0, 0);
    }
    __syncthreads();
    int cur = 0;

    for (int ks = 0; ks < nks; ks++) {
        const int kc2 = (ks + 1) << 5;
        if (ks + 1 < nks) {
            if constexpr (MODE == 3) { loadA32(kc2); stageB(kc2, cur ^ 1); }
            else { stageA_bf(kc2, cur ^ 1); stageB(kc2, cur ^ 1); }
        }

        bf16x8 a[4], bvec[4];
#pragma unroll
        for (int mf = 0; mf < 4; mf++) {
            int R = wm * 64 + mf * 16 + lo;
            a[mf] = *reinterpret_cast<const bf16x8*>(&Ab[cur][R * 32 + ((hi ^ ((R >> 1) & 3)) << 3)]);
        }
#pragma unroll
        for (int nf = 0; nf < 4; nf++) {
            int R = wn * 64 + nf * 16 + lo;
            bvec[nf] = *reinterpret_cast<const bf16x8*>(&Bb[cur][R * 32 + ((hi ^ ((R >> 1) & 3)) << 3)]);
        }
#pragma unroll
        for (int mf = 0; mf < 4; mf++)
#pragma unroll
            for (int nf = 0; nf < 4; nf++)
                acc[mf][nf] = __builtin_amdgcn_mfma_f32_16x16x32_bf16(a[mf], bvec[nf], acc[mf][nf], 0, 0, 0);

        if constexpr (MODE == 3) {
            if (ks + 1 < nks) writeA32(cur ^ 1);
        }
        __syncthreads();
        cur ^= 1;
    }

    const int mrow0 = m0 + wm * 64;

    if (MODE == 0) {
        const int ncol0 = n0g + wn * 64;
        float bs[4];
#pragma unroll
        for (int nf = 0; nf < 4; nf++) bs[nf] = biasQ[ncol0 + nf * 16 + lo];
#pragma unroll
        for (int mf = 0; mf < 4; mf++)
#pragma unroll
            for (int nf = 0; nf < 4; nf++)
#pragma unroll
                for (int r = 0; r < 4; r++) {
                    int row = mrow0 + mf * 16 + hi * 4 + r;
                    outf[(size_t)row * Ntot + ncol0 + nf * 16 + lo] = acc[mf][nf][r] + bs[nf];
                }
    } else {
        const int ncol0 = ((nt & 3) << 7) + wn * 64;   // within 512-wide segment
        const int h = ncol0 >> 6;
        const float* bias = (seg == 0) ? biasQ : (seg == 1) ? biasK : biasV;
        float bs[4];
#pragma unroll
        for (int nf = 0; nf < 4; nf++) bs[nf] = bias[ncol0 + nf * 16 + lo];

        if (seg < 2) {
            const float* scale = seg ? scale_k : scale_q;
            const int* pos = seg ? kpos : qpos;
            __bf16* dst0 = seg ? kh : qh;
            const float qmul = seg ? 1.0f : QSCALE;
            float sc4[4];
#pragma unroll
            for (int nf = 0; nf < 4; nf++) sc4[nf] = (1.0f + scale[nf * 16 + lo]) * qmul;
#pragma unroll
            for (int mf = 0; mf < 4; mf++) {
#pragma unroll
                for (int r = 0; r < 4; r++) {
                    int row = mrow0 + mf * 16 + hi * 4 + r;
                    float y0 = acc[mf][0][r] + bs[0];
                    float y1 = acc[mf][1][r] + bs[1];
                    float y2 = acc[mf][2][r] + bs[2];
                    float y3 = acc[mf][3][r] + bs[3];
                    float ps = y0 * y0 + y1 * y1 + y2 * y2 + y3 * y3;
#pragma unroll
                    for (int off = 1; off < 16; off <<= 1) ps += __shfl_xor(ps, off);
                    float rmsf = rsqrtf(ps * (1.0f / 64.0f) + 1e-6f);
                    int p = pos[row];
                    float2 c0 = rtab[p * 32 + lo];
                    float2 c1 = rtab[p * 32 + 16 + lo];
                    float z0 = y0 * rmsf * sc4[0];
                    float z1 = y1 * rmsf * sc4[1];
                    float z2 = y2 * rmsf * sc4[2];
                    float z3 = y3 * rmsf * sc4[3];
                    int b = row >> 11, t = row & (T_ - 1);
                    __bf16* dst = dst0 + ((size_t)(b * H_ + h) * T_ + t) * 64;
                    dst[lo]      = (__bf16)(z0 * c0.x - z2 * c0.y);
                    dst[16 + lo] = (__bf16)(z1 * c1.x - z3 * c1.y);
                    dst[32 + lo] = (__bf16)(z2 * c0.x + z0 * c0.y);
                    dst[48 + lo] = (__bf16)(z3 * c1.x + z1 * c1.y);
                }
            }
        } else {
#pragma unroll
            for (int mf = 0; mf < 4; mf++) {
                int row0 = mrow0 + mf * 16 + hi * 4;
                int b = row0 >> 11, t0 = row0 & (T_ - 1);
#pragma unroll
                for (int nf = 0; nf < 4; nf++) {
                    int d = nf * 16 + lo;
                    bf16x4 pk = { (__bf16)(acc[mf][nf][0] + bs[nf]), (__bf16)(acc[mf][nf][1] + bs[nf]),
                                  (__bf16)(acc[mf][nf][2] + bs[nf]), (__bf16)(acc[mf][nf][3] + bs[nf]) };
                    *reinterpret_cast<bf16x4*>(vt + ((size_t)(b * H_ + h) * 64 + d) * T_ + t0) = pk;
                }
            }
        }
    }
}

// ---------------- causal flash attention: fixed-shift softmax, 64-row strips ----------------
// qh (pre-scaled by QSCALE*RMSNorm), kh: bf16 [B*H][T][64]; vt: bf16 [B*H][64][T].
// Grid (x=bh 32, y=strip 32), sid = 31-blockIdx.y (longest first). Block = 4 waves.
// LDS = 16K(kbuf)+16K(vbuf)+8K(plds) = 40960 exactly -> 4 blocks/CU.
// plds: stride 64 + 16B-slot XOR swizzle (slot ^= lo&7) -> no padding, ~free banks.
__global__ __launch_bounds__(256, 4) void attn_kernel(const __bf16* __restrict__ qh,
                                                      const __bf16* __restrict__ kh,
                                                      const __bf16* __restrict__ vt,
                                                      __bf16* __restrict__ attn) {
    __shared__ __bf16 kbuf[2][64 * 64];
    __shared__ __bf16 vbuf[2][64 * 64];
    __shared__ __bf16 plds[4][16][64];

    const int lane = threadIdx.x & 63, widx = threadIdx.x >> 6;
    const int lo = lane & 15, hi = lane >> 4;
    const int bh = blockIdx.x;
    const int sid = 31 - blockIdx.y;          // longest strips dispatched first
    const int ntiles = sid + 1;
    const int qb = sid * 64 + widx * 16;
    const __bf16* Qg = qh + (size_t)bh * T_ * 64;
    const __bf16* Kg = kh + (size_t)bh * T_ * 64;
    const __bf16* Vg = vt + (size_t)bh * 64 * T_;
    const int b = bh >> 3, h = bh & 7;

    const int srow = lane >> 3;
    const int sslot = lane & 7;
    const int schunk = sslot ^ srow;

    bf16x8 qa[2];
#pragma unroll
    for (int c = 0; c < 2; c++)
        qa[c] = *reinterpret_cast<const bf16x8*>(Qg + (size_t)(qb + lo) * 64 + c * 32 + hi * 8);

    f32x4 o[4] = {};
    float l = 0.0f;
    const f32x4 minit = { -MSHIFT, -MSHIFT, -MSHIFT, -MSHIFT };

    auto stage = [&](int tile, int bufi) {
        const int kvb0 = tile * 64;
#pragma unroll
        for (int i = 0; i < 2; i++) {
            int r = widx * 16 + i * 8 + srow;
            gload_lds16(Kg + (size_t)(kvb0 + r) * 64 + schunk * 8,
                        &kbuf[bufi][(widx * 16 + i * 8) * 64]);
        }
#pragma unroll
        for (int i = 0; i < 2; i++) {
            int r = widx * 16 + i * 8 + srow;
            gload_lds16(Vg + (size_t)r * T_ + kvb0 + schunk * 8,
                        &vbuf[bufi][(widx * 16 + i * 8) * 64]);
        }
    };

    stage(0, 0);
    __syncthreads();
    int cur = 0;

    for (int j = 0; j < ntiles; ++j) {
        if (j + 1 < ntiles) stage(j + 1, cur ^ 1);

        // ---- S^T = K x Q^T (C-init = -MSHIFT): s[f][r] = S[q=lo][kv=16f+4hi+r] - 16 ----
        f32x4 s[4] = { minit, minit, minit, minit };
        __builtin_amdgcn_s_setprio(1);
#pragma unroll
        for (int c = 0; c < 2; c++) {
#pragma unroll
            for (int f = 0; f < 4; f++) {
                int R = f * 16 + lo;
                int C = c * 4 + hi;
                bf16x8 kb = *reinterpret_cast<const bf16x8*>(
                    &kbuf[cur][R * 64 + ((C ^ (lo & 7)) << 3)]);
                s[f] = __builtin_amdgcn_mfma_f32_16x16x32_bf16(kb, qa[c], s[f], 0, 0, 0);
            }
        }
        __builtin_amdgcn_s_setprio(0);

        // ---- mask (diag tile only) ----
        if (j == ntiles - 1) {
#pragma unroll
            for (int f = 0; f < 4; f++)
#pragma unroll
                for (int r = 0; r < 4; r++)
                    if (f * 16 + hi * 4 + r > widx * 16 + lo) s[f][r] = -1e30f;
        }

        // ---- P = exp2(s), in-lane + cross-half sum ----
        float ps = 0.0f;
        bf16x4 pk[4];
#pragma unroll
        for (int f = 0; f < 4; f++) {
#pragma unroll
            for (int r = 0; r < 4; r++) {
                float e = __builtin_amdgcn_exp2f(s[f][r]);
                ps += e;
                pk[f][r] = (__bf16)e;
            }
        }
        ps += __shfl_xor(ps, 16);
        ps += __shfl_xor(ps, 32);
        l += ps;

        // ---- P -> LDS (16B-slot XOR swizzle) -> B-fragments ----
#pragma unroll
        for (int f = 0; f < 4; f++)
            *reinterpret_cast<bf16x4*>(
                &plds[widx][lo][(((f * 2 + (hi >> 1)) ^ (lo & 7)) << 3) + ((hi & 1) << 2)]) = pk[f];
        bf16x8 pa0 = *reinterpret_cast<const bf16x8*>(&plds[widx][lo][((hi) ^ (lo & 7)) << 3]);
        bf16x8 pa1 = *reinterpret_cast<const bf16x8*>(&plds[widx][lo][((4 + hi) ^ (lo & 7)) << 3]);

        // ---- O^T += V^T x P^T ----
        __builtin_amdgcn_s_setprio(1);
#pragma unroll
        for (int n = 0; n < 4; n++) {
#pragma unroll
            for (int c = 0; c < 2; c++) {
                int R = n * 16 + lo;
                int C = c * 4 + hi;
                bf16x8 vb = *reinterpret_cast<const bf16x8*>(
                    &vbuf[cur][R * 64 + ((C ^ (lo & 7)) << 3)]);
                o[n] = __builtin_amdgcn_mfma_f32_16x16x32_bf16(vb, c ? pa1 : pa0, o[n], 0, 0, 0);
            }
        }
        __builtin_amdgcn_s_setprio(0);

        __syncthreads();
        cur ^= 1;
    }

    const float inv = 1.0f / l;
    const int qrow = qb + lo;
#pragma unroll
    for (int n = 0; n < 4; n++) {
        bf16x4 pko = { (__bf16)(o[n][0] * inv), (__bf16)(o[n][1] * inv),
                       (__bf16)(o[n][2] * inv), (__bf16)(o[n][3] * inv) };
        *reinterpret_cast<bf16x4*>(attn + ((size_t)b * T_ + qrow) * D_ + h * 64 + n * 16 + hi * 4) = pko;
    }
}

extern "C" void kernel_launch(void* const* d_in, const int* in_sizes, int n_in,
                              void* d_out, int out_size, void* d_ws, size_t ws_size,
                              hipStream_t stream) {
    const float* q  = (const float*)d_in[0];
    const float* kv = (const float*)d_in[1];
    const int* qpos = (const int*)d_in[3];
    const int* kpos = (const int*)d_in[4];
    const float* wq = (const float*)d_in[5];
    const float* bq = (const float*)d_in[6];
    const float* wk = (const float*)d_in[7];
    const float* bk = (const float*)d_in[8];
    const float* wv = (const float*)d_in[9];
    const float* bv = (const float*)d_in[10];
    const float* scale_q = (const float*)d_in[11];
    const float* scale_k = (const float*)d_in[12];
    const float* wo = (const float*)d_in[13];
    const float* bo = (const float*)d_in[14];
    float* out = (float*)d_out;

    char* ws = (char*)d_ws;
    size_t off = 0;
    auto alloc = [&](size_t bytes) {
        void* p = ws + off;
        off += (bytes + 255) & ~(size_t)255;
        return p;
    };
    const size_t MD = (size_t)B_ * T_ * D_;
    __bf16* wqkvT  = (__bf16*)alloc((size_t)3 * D_ * D_ * 2);
    __bf16* woT    = (__bf16*)alloc((size_t)D_ * D_ * 2);
    __bf16* qh    = (__bf16*)alloc(MD * 2);
    __bf16* kh    = (__bf16*)alloc(MD * 2);
    __bf16* vt    = (__bf16*)alloc(MD * 2);
    __bf16* attnb = (__bf16*)alloc(MD * 2);
    float2* rtab = (float2*)alloc((size_t)T_ * 32 * sizeof(float2));

    transpose_w4_kernel<<<dim3(16, 16, 4), 256, 0, stream>>>(wq, wk, wv, wo, wqkvT, woT);
    rope_table_kernel<<<(T_ * 32) / 256, 256, 0, stream>>>(rtab);

    const int M = B_ * T_;
    // fused QKV projection from fp32 activations (cast folded into A staging)
    gemm_tile_kernel<3><<<(M / 128) * (3 * D_ / 128), 256, 0, stream>>>(
        q, kv, nullptr, wqkvT, bq, bk, bv, nullptr, qh, kh, vt,
        scale_q, scale_k, qpos, kpos, rtab, M, 3 * D_, D_);
    // attention: grid (bh, strip), longest strips first; 64-row strips
    attn_kernel<<<dim3(B_ * H_, 32), 256, 0, stream>>>(qh, kh, vt, attnb);
    // output projection (bf16 A via global_load_lds)
    gemm_tile_kernel<0><<<(M / 128) * (D_ / 128), 256, 0, stream>>>(
        nullptr, nullptr, attnb, woT, bo, nullptr, nullptr, out, nullptr, nullptr, nullptr,
        nullptr, nullptr, nullptr, nullptr, nullptr, M, D_, D_);
}

// Round 10
// 84.247 us; speedup vs baseline: 1.4566x; 1.0158x over previous
//
#include <hip/hip_runtime.h>
#include <hip/hip_bf16.h>
#include <cstdint>

#define B_ 4
#define T_ 2048
#define D_ 512
#define H_ 8

typedef __bf16 bf16x8 __attribute__((ext_vector_type(8)));
typedef __bf16 bf16x4 __attribute__((ext_vector_type(4)));
typedef float f32x4 __attribute__((ext_vector_type(4)));

// 0.125 (1/sqrt(Dh)) * log2(e), folded into Q so softmax uses exp2 directly
#define QSCALE 0.18033688011112042f
// Fixed softmax shift: |S_exp2| <= ||q||*||k||*0.125*log2(e) ~= 13.4 < 16 (Cauchy-Schwarz
// with RMSNorm'd rows; RoPE is norm-preserving). exp2(s-16) in [2^-32, 1]: no overflow,
// no max tracking needed. Folded into the QK MFMA accumulator init.
#define MSHIFT 16.0f

__device__ inline void gload_lds16(const void* g, void* l) {
    __builtin_amdgcn_global_load_lds(
        (const __attribute__((address_space(1))) void*)g,
        (__attribute__((address_space(3))) void*)l, 16, 0, 0);
}

// ---------------- transpose all 4 weights (z selects) ----------------
__global__ void transpose_w4_kernel(const float* __restrict__ wq, const float* __restrict__ wk,
                                    const float* __restrict__ wv, const float* __restrict__ wo,
                                    __bf16* __restrict__ wqkvT, __bf16* __restrict__ woT) {
    __shared__ float tile[32][33];
    int z = blockIdx.z;
    const float* in = (z == 0) ? wq : (z == 1) ? wk : (z == 2) ? wv : wo;
    __bf16* out = (z < 3) ? wqkvT + (size_t)z * D_ * D_ : woT;
    int tx = threadIdx.x & 31, ty = threadIdx.x >> 5;
    int r0 = blockIdx.y * 32, c0 = blockIdx.x * 32;
#pragma unroll
    for (int i = 0; i < 4; i++)
        tile[ty + i * 8][tx] = in[(size_t)(r0 + ty + i * 8) * D_ + c0 + tx];
    __syncthreads();
#pragma unroll
    for (int i = 0; i < 4; i++)
        out[(size_t)(c0 + ty + i * 8) * D_ + r0 + tx] = (__bf16)tile[tx][ty + i * 8];
}

// ---------------- RoPE cos/sin table ----------------
__global__ void rope_table_kernel(float2* __restrict__ tab) {
    int i = blockIdx.x * 256 + threadIdx.x;     // T*32 entries
    int p = i >> 5, d2 = i & 31;
    float inv_ts = exp2f((float)d2 * (-13.28771237954945f / 32.0f));
    float ang = (float)p * inv_ts;
    float sv, cv;
    __sincosf(ang, &sv, &cv);
    tab[i] = make_float2(cv, sv);
}

// ---------------- tiled GEMM: 128x128 tile, BK=32, double-buffered LDS ----------------
// MODE 0: out = Xbf(bf16) @ woT^T + bo -> fp32 [M][512]; A via global_load_lds.
// MODE 3: fused QKV from FP32 activations; cast folded into A reg-staging with
//         DEPTH-2 prefetch: rLoad <- A(ks+2) issued at iter ks; writeA32 consumes
//         registers already drained by the previous barrier (no mid-iter vmcnt wait).
// LDS image identical in both modes: phys chunk slot s holds logical chunk
// s ^ ((row>>1)&3); read at (hi ^ ((row>>1)&3)).
template<int MODE>
__global__ __launch_bounds__(256, 2) void gemm_tile_kernel(
    const float* __restrict__ Aq32, const float* __restrict__ Akv32,
    const __bf16* __restrict__ Xbf,
    const __bf16* __restrict__ WT,
    const float* __restrict__ biasQ, const float* __restrict__ biasK,
    const float* __restrict__ biasV,
    float* __restrict__ outf, __bf16* __restrict__ qh, __bf16* __restrict__ kh,
    __bf16* __restrict__ vt,
    const float* __restrict__ scale_q, const float* __restrict__ scale_k,
    const int* __restrict__ qpos, const int* __restrict__ kpos,
    const float2* __restrict__ rtab, int M, int Ntot, int K) {
    __shared__ __bf16 Ab[2][128 * 32];
    __shared__ __bf16 Bb[2][128 * 32];

    const int tid = threadIdx.x;
    const int lane = tid & 63, widx = tid >> 6;
    const int lo = lane & 15, hi = lane >> 4;
    const int wm = widx >> 1, wn = widx & 1;

    // bijective XCD swizzle (gridDim.x % 8 == 0)
    const int nwg = gridDim.x;
    const int q8 = nwg >> 3;
    int bid = blockIdx.x;
    int swz = (bid & 7) * q8 + (bid >> 3);
    const int ntn = Ntot >> 7;
    const int m0 = (swz / ntn) << 7;
    const int nt = swz % ntn;
    const int n0g = nt << 7;                       // row base in WT
    const int seg = (MODE == 3) ? (nt >> 2) : 0;   // 0:Q 1:K 2:V

    const int srow = tid >> 2;
    const int sslot = tid & 3;

    const float* Af32 = (MODE == 3) ? ((seg > 0) ? Akv32 : Aq32) : nullptr;

    f32x4 acc[4][4] = {};

    auto stageB = [&](int kc, int bufi) {
#pragma unroll
        for (int i = 0; i < 2; i++) {
            int row = i * 64 + srow;
            int cs = sslot ^ ((row >> 1) & 3);
            gload_lds16(WT + (size_t)(n0g + row) * K + kc + cs * 8,
                        &Bb[bufi][(i * 64 + widx * 16) * 32]);
        }
    };
    auto stageA_bf = [&](int kc, int bufi) {
#pragma unroll
        for (int i = 0; i < 2; i++) {
            int row = i * 64 + srow;
            int cs = sslot ^ ((row >> 1) & 3);
            gload_lds16(Xbf + (size_t)(m0 + row) * K + kc + cs * 8,
                        &Ab[bufi][(i * 64 + widx * 16) * 32]);
        }
    };
    auto loadA32 = [&](float4 (&r)[2][2], int kc) {
#pragma unroll
        for (int i = 0; i < 2; i++) {
            const float* src = Af32 + (size_t)(m0 + i * 64 + srow) * K + kc + sslot * 8;
            r[i][0] = *reinterpret_cast<const float4*>(src);
            r[i][1] = *reinterpret_cast<const float4*>(src + 4);
        }
    };
    auto writeA32 = [&](float4 (&r)[2][2], int bufi) {
#pragma unroll
        for (int i = 0; i < 2; i++) {
            int row = i * 64 + srow;
            bf16x8 v = { (__bf16)r[i][0].x, (__bf16)r[i][0].y,
                         (__bf16)r[i][0].z, (__bf16)r[i][0].w,
                         (__bf16)r[i][1].x, (__bf16)r[i][1].y,
                         (__bf16)r[i][1].z, (__bf16)r[i][1].w };
            *reinterpret_cast<bf16x8*>(
                &Ab[bufi][row * 32 + ((sslot ^ ((row >> 1) & 3)) << 3)]) = v;
        }
    };
    auto compute = [&](int bufi) {
        bf16x8 a[4], bvec[4];
#pragma unroll
        for (int mf = 0; mf < 4; mf++) {
            int R = wm * 64 + mf * 16 + lo;
            a[mf] = *reinterpret_cast<const bf16x8*>(&Ab[bufi][R * 32 + ((hi ^ ((R >> 1) & 3)) << 3)]);
        }
#pragma unroll
        for (int nf = 0; nf < 4; nf++) {
            int R = wn * 64 + nf * 16 + lo;
            bvec[nf] = *reinterpret_cast<const bf16x8*>(&Bb[bufi][R * 32 + ((hi ^ ((R >> 1) & 3)) << 3)]);
        }
#pragma unroll
        for (int mf = 0; mf < 4; mf++)
#pragma unroll
            for (int nf = 0; nf < 4; nf++)
                acc[mf][nf] = __builtin_amdgcn_mfma_f32_16x16x32_bf16(a[mf], bvec[nf], acc[mf][nf], 0, 0, 0);
    };

    const int nks = K >> 5;
    int cur = 0;

    if constexpr (MODE == 3) {
        float4 rA[2][2], rB[2][2];
        auto step3 = [&](int ks, float4 (&rUse)[2][2], float4 (&rLoad)[2][2]) {
            if (ks + 2 < nks) loadA32(rLoad, (ks + 2) << 5);   // depth-2 prefetch
            if (ks + 1 < nks) stageB((ks + 1) << 5, cur ^ 1);
            compute(cur);
            if (ks + 1 < nks) writeA32(rUse, cur ^ 1);         // regs drained at prior barrier
            __syncthreads();
            cur ^= 1;
        };
        loadA32(rA, 0);
        stageB(0, 0);
        writeA32(rA, 0);          // only prologue pays a fresh vmcnt wait
        loadA32(rA, 32);          // A(1), drained by the sync below
        __syncthreads();
        for (int ks = 0; ks < nks; ks += 2) {   // nks even; static reg-set rotation
            step3(ks, rA, rB);
            step3(ks + 1, rB, rA);
        }
    } else {
        stageA_bf(0, 0); stageB(0, 0);
        __syncthreads();
        for (int ks = 0; ks < nks; ks++) {
            const int kc2 = (ks + 1) << 5;
            if (ks + 1 < nks) { stageA_bf(kc2, cur ^ 1); stageB(kc2, cur ^ 1); }
            compute(cur);
            __syncthreads();
            cur ^= 1;
        }
    }

    const int mrow0 = m0 + wm * 64;

    if (MODE == 0) {
        const int ncol0 = n0g + wn * 64;
        float bs[4];
#pragma unroll
        for (int nf = 0; nf < 4; nf++) bs[nf] = biasQ[ncol0 + nf * 16 + lo];
#pragma unroll
        for (int mf = 0; mf < 4; mf++)
#pragma unroll
            for (int nf = 0; nf < 4; nf++)
#pragma unroll
                for (int r = 0; r < 4; r++) {
                    int row = mrow0 + mf * 16 + hi * 4 + r;
                    outf[(size_t)row * Ntot + ncol0 + nf * 16 + lo] = acc[mf][nf][r] + bs[nf];
                }
    } else {
        const int ncol0 = ((nt & 3) << 7) + wn * 64;   // within 512-wide segment
        const int h = ncol0 >> 6;
        const float* bias = (seg == 0) ? biasQ : (seg == 1) ? biasK : biasV;
        float bs[4];
#pragma unroll
        for (int nf = 0; nf < 4; nf++) bs[nf] = bias[ncol0 + nf * 16 + lo];

        if (seg < 2) {
            const float* scale = seg ? scale_k : scale_q;
            const int* pos = seg ? kpos : qpos;
            __bf16* dst0 = seg ? kh : qh;
            const float qmul = seg ? 1.0f : QSCALE;
            float sc4[4];
#pragma unroll
            for (int nf = 0; nf < 4; nf++) sc4[nf] = (1.0f + scale[nf * 16 + lo]) * qmul;
#pragma unroll
            for (int mf = 0; mf < 4; mf++) {
#pragma unroll
                for (int r = 0; r < 4; r++) {
                    int row = mrow0 + mf * 16 + hi * 4 + r;
                    float y0 = acc[mf][0][r] + bs[0];
                    float y1 = acc[mf][1][r] + bs[1];
                    float y2 = acc[mf][2][r] + bs[2];
                    float y3 = acc[mf][3][r] + bs[3];
                    float ps = y0 * y0 + y1 * y1 + y2 * y2 + y3 * y3;
#pragma unroll
                    for (int off = 1; off < 16; off <<= 1) ps += __shfl_xor(ps, off);
                    float rmsf = rsqrtf(ps * (1.0f / 64.0f) + 1e-6f);
                    int p = pos[row];
                    float2 c0 = rtab[p * 32 + lo];
                    float2 c1 = rtab[p * 32 + 16 + lo];
                    float z0 = y0 * rmsf * sc4[0];
                    float z1 = y1 * rmsf * sc4[1];
                    float z2 = y2 * rmsf * sc4[2];
                    float z3 = y3 * rmsf * sc4[3];
                    int b = row >> 11, t = row & (T_ - 1);
                    __bf16* dst = dst0 + ((size_t)(b * H_ + h) * T_ + t) * 64;
                    dst[lo]      = (__bf16)(z0 * c0.x - z2 * c0.y);
                    dst[16 + lo] = (__bf16)(z1 * c1.x - z3 * c1.y);
                    dst[32 + lo] = (__bf16)(z2 * c0.x + z0 * c0.y);
                    dst[48 + lo] = (__bf16)(z3 * c1.x + z1 * c1.y);
                }
            }
        } else {
#pragma unroll
            for (int mf = 0; mf < 4; mf++) {
                int row0 = mrow0 + mf * 16 + hi * 4;
                int b = row0 >> 11, t0 = row0 & (T_ - 1);
#pragma unroll
                for (int nf = 0; nf < 4; nf++) {
                    int d = nf * 16 + lo;
                    bf16x4 pk = { (__bf16)(acc[mf][nf][0] + bs[nf]), (__bf16)(acc[mf][nf][1] + bs[nf]),
                                  (__bf16)(acc[mf][nf][2] + bs[nf]), (__bf16)(acc[mf][nf][3] + bs[nf]) };
                    *reinterpret_cast<bf16x4*>(vt + ((size_t)(b * H_ + h) * 64 + d) * T_ + t0) = pk;
                }
            }
        }
    }
}

// ---------------- causal flash attention: fixed-shift softmax, 64-row strips ----------------
// qh (pre-scaled by QSCALE*RMSNorm), kh: bf16 [B*H][T][64]; vt: bf16 [B*H][64][T].
// Grid (x=bh 32, y=strip 32), sid = 31-blockIdx.y (longest first). Block = 4 waves.
// LDS = 16K(kbuf)+16K(vbuf)+8K(plds) = 40960 exactly -> 4 blocks/CU.
// plds: stride 64 + 16B-slot XOR swizzle (slot ^= lo&7) -> no padding, ~free banks.
__global__ __launch_bounds__(256, 4) void attn_kernel(const __bf16* __restrict__ qh,
                                                      const __bf16* __restrict__ kh,
                                                      const __bf16* __restrict__ vt,
                                                      __bf16* __restrict__ attn) {
    __shared__ __bf16 kbuf[2][64 * 64];
    __shared__ __bf16 vbuf[2][64 * 64];
    __shared__ __bf16 plds[4][16][64];

    const int lane = threadIdx.x & 63, widx = threadIdx.x >> 6;
    const int lo = lane & 15, hi = lane >> 4;
    const int bh = blockIdx.x;
    const int sid = 31 - blockIdx.y;          // longest strips dispatched first
    const int ntiles = sid + 1;
    const int qb = sid * 64 + widx * 16;
    const __bf16* Qg = qh + (size_t)bh * T_ * 64;
    const __bf16* Kg = kh + (size_t)bh * T_ * 64;
    const __bf16* Vg = vt + (size_t)bh * 64 * T_;
    const int b = bh >> 3, h = bh & 7;

    const int srow = lane >> 3;
    const int sslot = lane & 7;
    const int schunk = sslot ^ srow;

    bf16x8 qa[2];
#pragma unroll
    for (int c = 0; c < 2; c++)
        qa[c] = *reinterpret_cast<const bf16x8*>(Qg + (size_t)(qb + lo) * 64 + c * 32 + hi * 8);

    f32x4 o[4] = {};
    float l = 0.0f;
    const f32x4 minit = { -MSHIFT, -MSHIFT, -MSHIFT, -MSHIFT };

    auto stage = [&](int tile, int bufi) {
        const int kvb0 = tile * 64;
#pragma unroll
        for (int i = 0; i < 2; i++) {
            int r = widx * 16 + i * 8 + srow;
            gload_lds16(Kg + (size_t)(kvb0 + r) * 64 + schunk * 8,
                        &kbuf[bufi][(widx * 16 + i * 8) * 64]);
        }
#pragma unroll
        for (int i = 0; i < 2; i++) {
            int r = widx * 16 + i * 8 + srow;
            gload_lds16(Vg + (size_t)r * T_ + kvb0 + schunk * 8,
                        &vbuf[bufi][(widx * 16 + i * 8) * 64]);
        }
    };

    stage(0, 0);
    __syncthreads();
    int cur = 0;

    for (int j = 0; j < ntiles; ++j) {
        if (j + 1 < ntiles) stage(j + 1, cur ^ 1);

        // ---- S^T = K x Q^T (C-init = -MSHIFT): s[f][r] = S[q=lo][kv=16f+4hi+r] - 16 ----
        f32x4 s[4] = { minit, minit, minit, minit };
        __builtin_amdgcn_s_setprio(1);
#pragma unroll
        for (int c = 0; c < 2; c++) {
#pragma unroll
            for (int f = 0; f < 4; f++) {
                int R = f * 16 + lo;
                int C = c * 4 + hi;
                bf16x8 kb = *reinterpret_cast<const bf16x8*>(
                    &kbuf[cur][R * 64 + ((C ^ (lo & 7)) << 3)]);
                s[f] = __builtin_amdgcn_mfma_f32_16x16x32_bf16(kb, qa[c], s[f], 0, 0, 0);
            }
        }
        __builtin_amdgcn_s_setprio(0);

        // ---- mask (diag tile only) ----
        if (j == ntiles - 1) {
#pragma unroll
            for (int f = 0; f < 4; f++)
#pragma unroll
                for (int r = 0; r < 4; r++)
                    if (f * 16 + hi * 4 + r > widx * 16 + lo) s[f][r] = -1e30f;
        }

        // ---- P = exp2(s), in-lane + cross-half sum ----
        float ps = 0.0f;
        bf16x4 pk[4];
#pragma unroll
        for (int f = 0; f < 4; f++) {
#pragma unroll
            for (int r = 0; r < 4; r++) {
                float e = __builtin_amdgcn_exp2f(s[f][r]);
                ps += e;
                pk[f][r] = (__bf16)e;
            }
        }
        ps += __shfl_xor(ps, 16);
        ps += __shfl_xor(ps, 32);
        l += ps;

        // ---- P -> LDS (16B-slot XOR swizzle) -> B-fragments ----
#pragma unroll
        for (int f = 0; f < 4; f++)
            *reinterpret_cast<bf16x4*>(
                &plds[widx][lo][(((f * 2 + (hi >> 1)) ^ (lo & 7)) << 3) + ((hi & 1) << 2)]) = pk[f];
        bf16x8 pa0 = *reinterpret_cast<const bf16x8*>(&plds[widx][lo][((hi) ^ (lo & 7)) << 3]);
        bf16x8 pa1 = *reinterpret_cast<const bf16x8*>(&plds[widx][lo][((4 + hi) ^ (lo & 7)) << 3]);

        // ---- O^T += V^T x P^T ----
        __builtin_amdgcn_s_setprio(1);
#pragma unroll
        for (int n = 0; n < 4; n++) {
#pragma unroll
            for (int c = 0; c < 2; c++) {
                int R = n * 16 + lo;
                int C = c * 4 + hi;
                bf16x8 vb = *reinterpret_cast<const bf16x8*>(
                    &vbuf[cur][R * 64 + ((C ^ (lo & 7)) << 3)]);
                o[n] = __builtin_amdgcn_mfma_f32_16x16x32_bf16(vb, c ? pa1 : pa0, o[n], 0, 0, 0);
            }
        }
        __builtin_amdgcn_s_setprio(0);

        __syncthreads();
        cur ^= 1;
    }

    const float inv = 1.0f / l;
    const int qrow = qb + lo;
#pragma unroll
    for (int n = 0; n < 4; n++) {
        bf16x4 pko = { (__bf16)(o[n][0] * inv), (__bf16)(o[n][1] * inv),
                       (__bf16)(o[n][2] * inv), (__bf16)(o[n][3] * inv) };
        *reinterpret_cast<bf16x4*>(attn + ((size_t)b * T_ + qrow) * D_ + h * 64 + n * 16 + hi * 4) = pko;
    }
}

extern "C" void kernel_launch(void* const* d_in, const int* in_sizes, int n_in,
                              void* d_out, int out_size, void* d_ws, size_t ws_size,
                              hipStream_t stream) {
    const float* q  = (const float*)d_in[0];
    const float* kv = (const float*)d_in[1];
    const int* qpos = (const int*)d_in[3];
    const int* kpos = (const int*)d_in[4];
    const float* wq = (const float*)d_in[5];
    const float* bq = (const float*)d_in[6];
    const float* wk = (const float*)d_in[7];
    const float* bk = (const float*)d_in[8];
    const float* wv = (const float*)d_in[9];
    const float* bv = (const float*)d_in[10];
    const float* scale_q = (const float*)d_in[11];
    const float* scale_k = (const float*)d_in[12];
    const float* wo = (const float*)d_in[13];
    const float* bo = (const float*)d_in[14];
    float* out = (float*)d_out;

    char* ws = (char*)d_ws;
    size_t off = 0;
    auto alloc = [&](size_t bytes) {
        void* p = ws + off;
        off += (bytes + 255) & ~(size_t)255;
        return p;
    };
    const size_t MD = (size_t)B_ * T_ * D_;
    __bf16* wqkvT  = (__bf16*)alloc((size_t)3 * D_ * D_ * 2);
    __bf16* woT    = (__bf16*)alloc((size_t)D_ * D_ * 2);
    __bf16* qh    = (__bf16*)alloc(MD * 2);
    __bf16* kh    = (__bf16*)alloc(MD * 2);
    __bf16* vt    = (__bf16*)alloc(MD * 2);
    __bf16* attnb = (__bf16*)alloc(MD * 2);
    float2* rtab = (float2*)alloc((size_t)T_ * 32 * sizeof(float2));

    transpose_w4_kernel<<<dim3(16, 16, 4), 256, 0, stream>>>(wq, wk, wv, wo, wqkvT, woT);
    rope_table_kernel<<<(T_ * 32) / 256, 256, 0, stream>>>(rtab);

    const int M = B_ * T_;
    // fused QKV projection from fp32 activations (cast folded into A staging, depth-2 prefetch)
    gemm_tile_kernel<3><<<(M / 128) * (3 * D_ / 128), 256, 0, stream>>>(
        q, kv, nullptr, wqkvT, bq, bk, bv, nullptr, qh, kh, vt,
        scale_q, scale_k, qpos, kpos, rtab, M, 3 * D_, D_);
    // attention: grid (bh, strip), longest strips first; 64-row strips
    attn_kernel<<<dim3(B_ * H_, 32), 256, 0, stream>>>(qh, kh, vt, attnb);
    // output projection (bf16 A via global_load_lds)
    gemm_tile_kernel<0><<<(M / 128) * (D_ / 128), 256, 0, stream>>>(
        nullptr, nullptr, attnb, woT, bo, nullptr, nullptr, out, nullptr, nullptr, nullptr,
        nullptr, nullptr, nullptr, nullptr, nullptr, M, D_, D_);
}